// Round 1
// baseline (771.898 us; speedup 1.0000x reference)
//
#include <hip/hip_runtime.h>
#include <math.h>

// Problem constants (from reference): IN_C = H*HID = 128, H = 2, HID = 64
#define FDIM 128
#define NEG_SLOPE 0.2f

__device__ __forceinline__ float lrelu(float x) {
    return x > 0.f ? x : NEG_SLOPE * x;
}

// ---------------- CSR build ----------------

__global__ __launch_bounds__(256) void k_degree(const int* __restrict__ srcp,
                                                const int* __restrict__ dstp,
                                                int E, int N, int* __restrict__ deg) {
    int e = blockIdx.x * 256 + threadIdx.x;
    int total = E + N;
    if (e >= total) return;
    int d = (e < E) ? dstp[e] : (e - E);
    atomicAdd(&deg[d], 1);
}

// single-block exclusive scan: rowp[0]=0, rowp[i+1]=sum(deg[0..i])
__global__ __launch_bounds__(256) void k_scan(const int* __restrict__ deg,
                                              int* __restrict__ rowp, int n) {
    __shared__ int sh[256];
    int t = threadIdx.x;
    int chunk = (n + 255) >> 8;
    int b = t * chunk;
    int e = min(b + chunk, n);
    int s = 0;
    for (int i = b; i < e; ++i) s += deg[i];
    sh[t] = s;
    __syncthreads();
    for (int off = 1; off < 256; off <<= 1) {
        int v = (t >= off) ? sh[t - off] : 0;
        __syncthreads();
        sh[t] += v;
        __syncthreads();
    }
    int run = (t == 0) ? 0 : sh[t - 1];
    if (t == 0) rowp[0] = 0;
    for (int i = b; i < e; ++i) { run += deg[i]; rowp[i + 1] = run; }
}

__global__ __launch_bounds__(256) void k_scatter(const int* __restrict__ srcp,
                                                 const int* __restrict__ dstp,
                                                 int E, int N,
                                                 const int* __restrict__ rowp,
                                                 int* __restrict__ cnt,
                                                 int* __restrict__ col) {
    int e = blockIdx.x * 256 + threadIdx.x;
    int total = E + N;
    if (e >= total) return;
    int s, d;
    if (e < E) { s = srcp[e]; d = dstp[e]; }
    else       { s = d = e - E; }
    int pos = rowp[d] + atomicAdd(&cnt[d], 1);
    col[pos] = s;
}

// ---------------- GEMM: out[n][c] = sum_k A[n][k] * W[k][c]  (K=128, C=128) ----------------
// 256 threads, 64 rows/block, thread = 8 rows x 4 cols. W staged in LDS (64 KB).

__global__ __launch_bounds__(256) void k_gemm(const float* __restrict__ A,
                                              const float* __restrict__ W,
                                              float* __restrict__ out, int nrows) {
    __shared__ float Ws[FDIM * FDIM];
    int t = threadIdx.x;
    for (int f = t; f < FDIM * FDIM / 4; f += 256)
        ((float4*)Ws)[f] = ((const float4*)W)[f];
    __syncthreads();

    int tx = t & 31;       // cols tx*4 .. tx*4+3
    int ty = t >> 5;       // rows ty*8 .. ty*8+7
    int row0 = blockIdx.x * 64 + ty * 8;

    float acc[8][4];
#pragma unroll
    for (int i = 0; i < 8; ++i)
#pragma unroll
        for (int j = 0; j < 4; ++j) acc[i][j] = 0.f;

    int rr[8];
#pragma unroll
    for (int i = 0; i < 8; ++i)
        rr[i] = (row0 + i < nrows) ? (row0 + i) : (nrows - 1);

#pragma unroll 2
    for (int k4 = 0; k4 < FDIM; k4 += 4) {
        float4 xv[8];
#pragma unroll
        for (int i = 0; i < 8; ++i)
            xv[i] = *(const float4*)(A + (size_t)rr[i] * FDIM + k4);
#pragma unroll
        for (int q = 0; q < 4; ++q) {
            float4 wv = *(float4*)&Ws[(k4 + q) * FDIM + tx * 4];
#pragma unroll
            for (int i = 0; i < 8; ++i) {
                float xs = (q == 0) ? xv[i].x : (q == 1) ? xv[i].y : (q == 2) ? xv[i].z : xv[i].w;
                acc[i][0] = fmaf(xs, wv.x, acc[i][0]);
                acc[i][1] = fmaf(xs, wv.y, acc[i][1]);
                acc[i][2] = fmaf(xs, wv.z, acc[i][2]);
                acc[i][3] = fmaf(xs, wv.w, acc[i][3]);
            }
        }
    }
#pragma unroll
    for (int i = 0; i < 8; ++i) {
        if (row0 + i < nrows)
            *(float4*)(out + (size_t)(row0 + i) * FDIM + tx * 4) =
                make_float4(acc[i][0], acc[i][1], acc[i][2], acc[i][3]);
    }
}

// ---------------- attention scalars: asrc[n][h], adst[n][h] ----------------
// one wave per (node, head)

__global__ __launch_bounds__(256) void k_att(const float* __restrict__ h,
                                             const float* __restrict__ att_s,
                                             const float* __restrict__ att_d,
                                             float* __restrict__ asrc,
                                             float* __restrict__ adst, int n) {
    int w = (blockIdx.x * 256 + threadIdx.x) >> 6;
    int lane = threadIdx.x & 63;
    int node = w >> 1, head = w & 1;
    if (node >= n) return;
    float v = h[(size_t)node * FDIM + head * 64 + lane];
    float pa = v * att_s[head * 64 + lane];
    float pd = v * att_d[head * 64 + lane];
#pragma unroll
    for (int off = 32; off; off >>= 1) {
        pa += __shfl_xor(pa, off);
        pd += __shfl_xor(pd, off);
    }
    if (lane == 0) {
        asrc[node * 2 + head] = pa;
        adst[node * 2 + head] = pd;
    }
}

// ---------------- per-dst softmax + aggregation (one wave per node) ----------------
// lane c owns channels c (head 0) and c+64 (head 1).
// epilogue: +bias, ReLU; optionally fused fc + sigmoid (layer 2).

__global__ __launch_bounds__(256) void k_aggregate(const float* __restrict__ h,
                                                   const float* __restrict__ asrc,
                                                   const float* __restrict__ adst,
                                                   const int* __restrict__ rowp,
                                                   const int* __restrict__ col,
                                                   const float* __restrict__ bias,
                                                   float* __restrict__ outbuf,
                                                   const float* __restrict__ fcW,
                                                   const float* __restrict__ fcb,
                                                   float* __restrict__ outfin, int n) {
    int node = (blockIdx.x * 256 + threadIdx.x) >> 6;
    int lane = threadIdx.x & 63;
    if (node >= n) return;
    int start = rowp[node], end = rowp[node + 1];
    float ad0 = adst[2 * node], ad1 = adst[2 * node + 1];

    // pass 1: segment max (lanes parallel over edges)
    float m0 = -1e30f, m1 = -1e30f;
    for (int e = start + lane; e < end; e += 64) {
        int s = col[e];
        float v0 = lrelu(asrc[2 * s] + ad0);
        float v1 = lrelu(asrc[2 * s + 1] + ad1);
        m0 = fmaxf(m0, v0);
        m1 = fmaxf(m1, v1);
    }
#pragma unroll
    for (int off = 32; off; off >>= 1) {
        m0 = fmaxf(m0, __shfl_xor(m0, off));
        m1 = fmaxf(m1, __shfl_xor(m1, off));
    }

    // pass 2: segment sum of exp
    float s0 = 0.f, s1 = 0.f;
    for (int e = start + lane; e < end; e += 64) {
        int s = col[e];
        float v0 = lrelu(asrc[2 * s] + ad0);
        float v1 = lrelu(asrc[2 * s + 1] + ad1);
        s0 += __expf(v0 - m0);
        s1 += __expf(v1 - m1);
    }
#pragma unroll
    for (int off = 32; off; off >>= 1) {
        s0 += __shfl_xor(s0, off);
        s1 += __shfl_xor(s1, off);
    }
    float inv0 = 1.f / (s0 + 1e-16f);
    float inv1 = 1.f / (s1 + 1e-16f);

    // pass 3: weighted aggregation, lane-per-channel
    float acc0 = 0.f, acc1 = 0.f;
    for (int e = start; e < end; ++e) {
        int s = col[e];
        float v0 = lrelu(asrc[2 * s] + ad0);
        float v1 = lrelu(asrc[2 * s + 1] + ad1);
        float al0 = __expf(v0 - m0) * inv0;
        float al1 = __expf(v1 - m1) * inv1;
        acc0 = fmaf(h[(size_t)s * FDIM + lane], al0, acc0);
        acc1 = fmaf(h[(size_t)s * FDIM + 64 + lane], al1, acc1);
    }

    float o0 = fmaxf(acc0 + bias[lane], 0.f);
    float o1 = fmaxf(acc1 + bias[64 + lane], 0.f);
    if (outbuf) {
        outbuf[(size_t)node * FDIM + lane] = o0;
        outbuf[(size_t)node * FDIM + 64 + lane] = o1;
    }
    if (outfin) {
        float p = fmaf(o0, fcW[lane], o1 * fcW[64 + lane]);
#pragma unroll
        for (int off = 32; off; off >>= 1) p += __shfl_xor(p, off);
        if (lane == 0) outfin[node] = 1.f / (1.f + __expf(-(p + fcb[0])));
    }
}

// ---------------- host ----------------

extern "C" void kernel_launch(void* const* d_in, const int* in_sizes, int n_in,
                              void* d_out, int out_size, void* d_ws, size_t ws_size,
                              hipStream_t stream) {
    const float* x    = (const float*)d_in[0];
    const int*   ei   = (const int*)d_in[1];
    const float* W1   = (const float*)d_in[3];
    const float* as1  = (const float*)d_in[4];
    const float* ad1  = (const float*)d_in[5];
    const float* b1   = (const float*)d_in[6];
    const float* W2   = (const float*)d_in[7];
    const float* as2  = (const float*)d_in[8];
    const float* ad2  = (const float*)d_in[9];
    const float* b2   = (const float*)d_in[10];
    const float* fcW  = (const float*)d_in[11];
    const float* fcb  = (const float*)d_in[12];

    int N = in_sizes[0] / FDIM;
    int E = in_sizes[2];
    int E2 = E + N;
    const int* srcp = ei;
    const int* dstp = ei + E;

    // workspace layout
    char* w = (char*)d_ws;
    float* hbuf = (float*)w;            w += (size_t)N * FDIM * sizeof(float);
    float* obuf = (float*)w;            w += (size_t)N * FDIM * sizeof(float);
    float* asrc = (float*)w;            w += (size_t)N * 2 * sizeof(float);
    float* adst = (float*)w;            w += (size_t)N * 2 * sizeof(float);
    int* rowp = (int*)w;                w += (size_t)(N + 1) * sizeof(int);
    int* deg  = (int*)w;                w += (size_t)N * sizeof(int);
    int* cnt  = (int*)w;                w += (size_t)N * sizeof(int);
    int* col  = (int*)w;                w += (size_t)E2 * sizeof(int);

    int egrid = (E2 + 255) / 256;
    int ggrid = (N + 63) / 64;
    int agrid = (N * 2 + 3) / 4;   // k_att: 4 waves/block, N*2 (node,head) waves
    int ngrid = (N + 3) / 4;       // k_aggregate: 4 waves/block

    // CSR build (shared by both layers)
    hipMemsetAsync(deg, 0, (size_t)N * sizeof(int), stream);
    hipMemsetAsync(cnt, 0, (size_t)N * sizeof(int), stream);
    k_degree<<<egrid, 256, 0, stream>>>(srcp, dstp, E, N, deg);
    k_scan<<<1, 256, 0, stream>>>(deg, rowp, N);
    k_scatter<<<egrid, 256, 0, stream>>>(srcp, dstp, E, N, rowp, cnt, col);

    // layer 1
    k_gemm<<<ggrid, 256, 0, stream>>>(x, W1, hbuf, N);
    k_att<<<agrid, 256, 0, stream>>>(hbuf, as1, ad1, asrc, adst, N);
    k_aggregate<<<ngrid, 256, 0, stream>>>(hbuf, asrc, adst, rowp, col, b1,
                                           obuf, nullptr, nullptr, nullptr, N);

    // layer 2 (fc + sigmoid fused into epilogue)
    k_gemm<<<ggrid, 256, 0, stream>>>(obuf, W2, hbuf, N);
    k_att<<<agrid, 256, 0, stream>>>(hbuf, as2, ad2, asrc, adst, N);
    k_aggregate<<<ngrid, 256, 0, stream>>>(hbuf, asrc, adst, rowp, col, b2,
                                           nullptr, fcW, fcb, (float*)d_out, N);
}

// Round 2
// 683.249 us; speedup vs baseline: 1.1297x; 1.1297x over previous
//
#include <hip/hip_runtime.h>
#include <math.h>

// Problem constants (from reference): IN_C = H*HID = 128, H = 2, HID = 64
#define FDIM 128
#define NEG_SLOPE 0.2f

__device__ __forceinline__ float lrelu(float x) {
    return x > 0.f ? x : NEG_SLOPE * x;
}

// ---------------- CSR build ----------------

__global__ __launch_bounds__(256) void k_degree(const int* __restrict__ srcp,
                                                const int* __restrict__ dstp,
                                                int E, int N, int* __restrict__ deg) {
    int e = blockIdx.x * 256 + threadIdx.x;
    int total = E + N;
    if (e >= total) return;
    int d = (e < E) ? dstp[e] : (e - E);
    atomicAdd(&deg[d], 1);
}

// single-block exclusive scan: rowp[0]=0, rowp[i+1]=sum(deg[0..i])
__global__ __launch_bounds__(256) void k_scan(const int* __restrict__ deg,
                                              int* __restrict__ rowp, int n) {
    __shared__ int sh[256];
    int t = threadIdx.x;
    int chunk = (n + 255) >> 8;
    int b = t * chunk;
    int e = min(b + chunk, n);
    int s = 0;
    for (int i = b; i < e; ++i) s += deg[i];
    sh[t] = s;
    __syncthreads();
    for (int off = 1; off < 256; off <<= 1) {
        int v = (t >= off) ? sh[t - off] : 0;
        __syncthreads();
        sh[t] += v;
        __syncthreads();
    }
    int run = (t == 0) ? 0 : sh[t - 1];
    if (t == 0) rowp[0] = 0;
    for (int i = b; i < e; ++i) { run += deg[i]; rowp[i + 1] = run; }
}

__global__ __launch_bounds__(256) void k_scatter(const int* __restrict__ srcp,
                                                 const int* __restrict__ dstp,
                                                 int E, int N,
                                                 const int* __restrict__ rowp,
                                                 int* __restrict__ cnt,
                                                 int* __restrict__ col) {
    int e = blockIdx.x * 256 + threadIdx.x;
    int total = E + N;
    if (e >= total) return;
    int s, d;
    if (e < E) { s = srcp[e]; d = dstp[e]; }
    else       { s = d = e - E; }
    int pos = rowp[d] + atomicAdd(&cnt[d], 1);
    col[pos] = s;
}

// ---------------- GEMM: out[n][c] = sum_k A[n][k] * W[k][c]  (K=128, C=128) ----------------

__global__ __launch_bounds__(256) void k_gemm(const float* __restrict__ A,
                                              const float* __restrict__ W,
                                              float* __restrict__ out, int nrows) {
    __shared__ float Ws[FDIM * FDIM];
    int t = threadIdx.x;
    for (int f = t; f < FDIM * FDIM / 4; f += 256)
        ((float4*)Ws)[f] = ((const float4*)W)[f];
    __syncthreads();

    int tx = t & 31;       // cols tx*4 .. tx*4+3
    int ty = t >> 5;       // rows ty*8 .. ty*8+7
    int row0 = blockIdx.x * 64 + ty * 8;

    float acc[8][4];
#pragma unroll
    for (int i = 0; i < 8; ++i)
#pragma unroll
        for (int j = 0; j < 4; ++j) acc[i][j] = 0.f;

    int rr[8];
#pragma unroll
    for (int i = 0; i < 8; ++i)
        rr[i] = (row0 + i < nrows) ? (row0 + i) : (nrows - 1);

#pragma unroll 2
    for (int k4 = 0; k4 < FDIM; k4 += 4) {
        float4 xv[8];
#pragma unroll
        for (int i = 0; i < 8; ++i)
            xv[i] = *(const float4*)(A + (size_t)rr[i] * FDIM + k4);
#pragma unroll
        for (int q = 0; q < 4; ++q) {
            float4 wv = *(float4*)&Ws[(k4 + q) * FDIM + tx * 4];
#pragma unroll
            for (int i = 0; i < 8; ++i) {
                float xs = (q == 0) ? xv[i].x : (q == 1) ? xv[i].y : (q == 2) ? xv[i].z : xv[i].w;
                acc[i][0] = fmaf(xs, wv.x, acc[i][0]);
                acc[i][1] = fmaf(xs, wv.y, acc[i][1]);
                acc[i][2] = fmaf(xs, wv.z, acc[i][2]);
                acc[i][3] = fmaf(xs, wv.w, acc[i][3]);
            }
        }
    }
#pragma unroll
    for (int i = 0; i < 8; ++i) {
        if (row0 + i < nrows)
            *(float4*)(out + (size_t)(row0 + i) * FDIM + tx * 4) =
                make_float4(acc[i][0], acc[i][1], acc[i][2], acc[i][3]);
    }
}

// ---------------- attention scalars: asrc[n][h], adst[n][h] ----------------

__global__ __launch_bounds__(256) void k_att(const float* __restrict__ h,
                                             const float* __restrict__ att_s,
                                             const float* __restrict__ att_d,
                                             float* __restrict__ asrc,
                                             float* __restrict__ adst, int n) {
    int w = (blockIdx.x * 256 + threadIdx.x) >> 6;
    int lane = threadIdx.x & 63;
    int node = w >> 1, head = w & 1;
    if (node >= n) return;
    float v = h[(size_t)node * FDIM + head * 64 + lane];
    float pa = v * att_s[head * 64 + lane];
    float pd = v * att_d[head * 64 + lane];
#pragma unroll
    for (int off = 32; off; off >>= 1) {
        pa += __shfl_xor(pa, off);
        pd += __shfl_xor(pd, off);
    }
    if (lane == 0) {
        asrc[node * 2 + head] = pa;
        adst[node * 2 + head] = pd;
    }
}

// ---------------- per-dst softmax + aggregation: ONE BLOCK (4 waves) PER NODE ----------------
// Phase A: 256-lane-parallel segment max.  Phase B: 256-lane-parallel sum of exp.
// Phase C: alpha for a 256-edge chunk computed ONCE into LDS, then 4 waves split the
//          gather loop (each wave every 4th edge, float2 gathers, lane c = channels 2c,2c+1).
// Epilogue (wave 0): +bias, ReLU, optional fused fc + sigmoid.

__global__ __launch_bounds__(256) void k_aggregate(const float* __restrict__ h,
                                                   const float* __restrict__ asrc,
                                                   const float* __restrict__ adst,
                                                   const int* __restrict__ rowp,
                                                   const int* __restrict__ col,
                                                   const float* __restrict__ bias,
                                                   float* __restrict__ outbuf,
                                                   const float* __restrict__ fcW,
                                                   const float* __restrict__ fcb,
                                                   float* __restrict__ outfin, int n) {
    __shared__ int    scol[256];
    __shared__ float2 salpha[256];
    __shared__ float  sred[8];
    __shared__ float2 sacc[4][64];

    int node = blockIdx.x;
    if (node >= n) return;
    int t = threadIdx.x;
    int w = t >> 6;
    int lane = t & 63;
    int start = rowp[node], end = rowp[node + 1];
    int deg = end - start;
    float ad0 = adst[2 * node], ad1 = adst[2 * node + 1];

    // ---- Phase A: segment max (256-parallel) ----
    float m0 = -1e30f, m1 = -1e30f;
    for (int i = t; i < deg; i += 256) {
        int s = col[start + i];
        m0 = fmaxf(m0, lrelu(asrc[2 * s] + ad0));
        m1 = fmaxf(m1, lrelu(asrc[2 * s + 1] + ad1));
    }
#pragma unroll
    for (int off = 32; off; off >>= 1) {
        m0 = fmaxf(m0, __shfl_xor(m0, off));
        m1 = fmaxf(m1, __shfl_xor(m1, off));
    }
    if (lane == 0) { sred[w] = m0; sred[4 + w] = m1; }
    __syncthreads();
    m0 = fmaxf(fmaxf(sred[0], sred[1]), fmaxf(sred[2], sred[3]));
    m1 = fmaxf(fmaxf(sred[4], sred[5]), fmaxf(sred[6], sred[7]));
    __syncthreads();

    // ---- Phase B: sum of exp (256-parallel) ----
    float s0 = 0.f, s1 = 0.f;
    for (int i = t; i < deg; i += 256) {
        int s = col[start + i];
        s0 += __expf(lrelu(asrc[2 * s] + ad0) - m0);
        s1 += __expf(lrelu(asrc[2 * s + 1] + ad1) - m1);
    }
#pragma unroll
    for (int off = 32; off; off >>= 1) {
        s0 += __shfl_xor(s0, off);
        s1 += __shfl_xor(s1, off);
    }
    if (lane == 0) { sred[w] = s0; sred[4 + w] = s1; }
    __syncthreads();
    float inv0 = 1.f / (sred[0] + sred[1] + sred[2] + sred[3] + 1e-16f);
    float inv1 = 1.f / (sred[4] + sred[5] + sred[6] + sred[7] + 1e-16f);
    __syncthreads();

    // ---- Phase C: chunked alpha-in-LDS + 4-way-split gather loop ----
    float2 acc = make_float2(0.f, 0.f);
    for (int base = 0; base < deg; base += 256) {
        int cnt = min(256, deg - base);
        if (t < cnt) {
            int s = col[start + base + t];
            scol[t] = s;
            salpha[t] = make_float2(
                __expf(lrelu(asrc[2 * s] + ad0) - m0) * inv0,
                __expf(lrelu(asrc[2 * s + 1] + ad1) - m1) * inv1);
        }
        __syncthreads();
#pragma unroll 2
        for (int i = w; i < cnt; i += 4) {
            int s = scol[i];
            float2 al = salpha[i];
            float a = (lane < 32) ? al.x : al.y;
            float2 hv = *(const float2*)(h + (size_t)s * FDIM + 2 * lane);
            acc.x = fmaf(hv.x, a, acc.x);
            acc.y = fmaf(hv.y, a, acc.y);
        }
        __syncthreads();
    }

    // ---- cross-wave accumulator reduce + epilogue ----
    sacc[w][lane] = acc;
    __syncthreads();
    if (w == 0) {
        float ax = sacc[0][lane].x + sacc[1][lane].x + sacc[2][lane].x + sacc[3][lane].x;
        float ay = sacc[0][lane].y + sacc[1][lane].y + sacc[2][lane].y + sacc[3][lane].y;
        int c0 = 2 * lane, c1 = 2 * lane + 1;
        float o0 = fmaxf(ax + bias[c0], 0.f);
        float o1 = fmaxf(ay + bias[c1], 0.f);
        if (outbuf)
            *(float2*)(outbuf + (size_t)node * FDIM + c0) = make_float2(o0, o1);
        if (outfin) {
            float p = fmaf(o0, fcW[c0], o1 * fcW[c1]);
#pragma unroll
            for (int off = 32; off; off >>= 1) p += __shfl_xor(p, off);
            if (lane == 0) outfin[node] = 1.f / (1.f + __expf(-(p + fcb[0])));
        }
    }
}

// ---------------- host ----------------

extern "C" void kernel_launch(void* const* d_in, const int* in_sizes, int n_in,
                              void* d_out, int out_size, void* d_ws, size_t ws_size,
                              hipStream_t stream) {
    const float* x    = (const float*)d_in[0];
    const int*   ei   = (const int*)d_in[1];
    const float* W1   = (const float*)d_in[3];
    const float* as1  = (const float*)d_in[4];
    const float* ad1  = (const float*)d_in[5];
    const float* b1   = (const float*)d_in[6];
    const float* W2   = (const float*)d_in[7];
    const float* as2  = (const float*)d_in[8];
    const float* ad2  = (const float*)d_in[9];
    const float* b2   = (const float*)d_in[10];
    const float* fcW  = (const float*)d_in[11];
    const float* fcb  = (const float*)d_in[12];

    int N = in_sizes[0] / FDIM;
    int E = in_sizes[2];
    int E2 = E + N;
    const int* srcp = ei;
    const int* dstp = ei + E;

    // workspace layout
    char* w = (char*)d_ws;
    float* hbuf = (float*)w;            w += (size_t)N * FDIM * sizeof(float);
    float* obuf = (float*)w;            w += (size_t)N * FDIM * sizeof(float);
    float* asrc = (float*)w;            w += (size_t)N * 2 * sizeof(float);
    float* adst = (float*)w;            w += (size_t)N * 2 * sizeof(float);
    int* rowp = (int*)w;                w += (size_t)(N + 1) * sizeof(int);
    int* deg  = (int*)w;                w += (size_t)N * sizeof(int);
    int* cnt  = (int*)w;                w += (size_t)N * sizeof(int);
    int* col  = (int*)w;                w += (size_t)E2 * sizeof(int);

    int egrid = (E2 + 255) / 256;
    int ggrid = (N + 63) / 64;
    int agrid = (N * 2 + 3) / 4;   // k_att: 4 waves/block

    // CSR build (shared by both layers)
    hipMemsetAsync(deg, 0, (size_t)N * sizeof(int), stream);
    hipMemsetAsync(cnt, 0, (size_t)N * sizeof(int), stream);
    k_degree<<<egrid, 256, 0, stream>>>(srcp, dstp, E, N, deg);
    k_scan<<<1, 256, 0, stream>>>(deg, rowp, N);
    k_scatter<<<egrid, 256, 0, stream>>>(srcp, dstp, E, N, rowp, cnt, col);

    // layer 1
    k_gemm<<<ggrid, 256, 0, stream>>>(x, W1, hbuf, N);
    k_att<<<agrid, 256, 0, stream>>>(hbuf, as1, ad1, asrc, adst, N);
    k_aggregate<<<N, 256, 0, stream>>>(hbuf, asrc, adst, rowp, col, b1,
                                       obuf, nullptr, nullptr, nullptr, N);

    // layer 2 (fc + sigmoid fused into epilogue)
    k_gemm<<<ggrid, 256, 0, stream>>>(obuf, W2, hbuf, N);
    k_att<<<agrid, 256, 0, stream>>>(hbuf, as2, ad2, asrc, adst, N);
    k_aggregate<<<N, 256, 0, stream>>>(hbuf, asrc, adst, rowp, col, b2,
                                       nullptr, fcW, fcb, (float*)d_out, N);
}

// Round 3
// 529.782 us; speedup vs baseline: 1.4570x; 1.2897x over previous
//
#include <hip/hip_runtime.h>
#include <math.h>

#define FDIM 128
#define NEG_SLOPE 0.2f

__device__ __forceinline__ float lrelu(float x) {
    return x > 0.f ? x : NEG_SLOPE * x;
}

// ---------------- CSR build ----------------

__global__ __launch_bounds__(256) void k_hist(const int* __restrict__ dstp,
                                              int E, int N, int* __restrict__ deg) {
    int e = blockIdx.x * 256 + threadIdx.x;
    int total = E + N;
    if (e >= total) return;
    int d = (e < E) ? dstp[e] : (e - E);
    atomicAdd(&deg[d], 1);
}

// hierarchical scan: local (1024/block) -> mid (block sums) -> add offsets
__global__ __launch_bounds__(256) void k_scan_local(const int* __restrict__ deg,
                                                    int* __restrict__ rowp,
                                                    int* __restrict__ bsum, int n) {
    __shared__ int sh[256];
    int b = blockIdx.x, t = threadIdx.x;
    int base = b * 1024 + t * 4;
    int4 v = make_int4(0, 0, 0, 0);
    if (base + 3 < n) v = *(const int4*)(deg + base);
    else {
        if (base < n)     v.x = deg[base];
        if (base + 1 < n) v.y = deg[base + 1];
        if (base + 2 < n) v.z = deg[base + 2];
        if (base + 3 < n) v.w = deg[base + 3];
    }
    int s = v.x + v.y + v.z + v.w;
    sh[t] = s;
    __syncthreads();
    for (int off = 1; off < 256; off <<= 1) {
        int u = (t >= off) ? sh[t - off] : 0;
        __syncthreads();
        sh[t] += u;
        __syncthreads();
    }
    int excl = t ? sh[t - 1] : 0;
    int r0 = excl + v.x, r1 = r0 + v.y, r2 = r1 + v.z, r3 = r2 + v.w;
    if (base < n)     rowp[base + 1] = r0;
    if (base + 1 < n) rowp[base + 2] = r1;
    if (base + 2 < n) rowp[base + 3] = r2;
    if (base + 3 < n) rowp[base + 4] = r3;
    if (t == 255) bsum[b] = sh[255];
}

__global__ void k_scan_mid(int* __restrict__ bsum, int nb) {
    int lane = threadIdx.x;  // single wave of 64
    int own = (lane < nb) ? bsum[lane] : 0;
    int v = own;
    for (int off = 1; off < 64; off <<= 1) {
        int u = __shfl(v, lane - off);
        if (lane >= off) v += u;
    }
    if (lane < nb) bsum[lane] = v - own;  // exclusive
}

__global__ __launch_bounds__(256) void k_scan_add(const int* __restrict__ bsum,
                                                  int* __restrict__ rowp, int n) {
    int idx = blockIdx.x * 256 + threadIdx.x;
    if (idx > n) return;
    if (idx == 0) { rowp[0] = 0; return; }
    int blk = (idx - 1) >> 10;
    if (blk > 0) rowp[idx] += bsum[blk];
}

__global__ __launch_bounds__(256) void k_scatter(const int* __restrict__ srcp,
                                                 const int* __restrict__ dstp,
                                                 int E, int N,
                                                 const int* __restrict__ rowp,
                                                 int* __restrict__ cnt,
                                                 int* __restrict__ col) {
    int e = blockIdx.x * 256 + threadIdx.x;
    int total = E + N;
    if (e >= total) return;
    int s, d;
    if (e < E) { s = srcp[e]; d = dstp[e]; }
    else       { s = d = e - E; }
    int pos = rowp[d] + atomicAdd(&cnt[d], 1);
    col[pos] = s;
}

// ---------------- GEMM (+ fused attention scalars): 64 rows/block ----------------
// out[n][c] = sum_k A[n][k] * W[k][c]; asrc[n][h] = sum_c out[n][c]*att_s[c] per head.

__global__ __launch_bounds__(256) void k_gemm(const float* __restrict__ A,
                                              const float* __restrict__ W,
                                              float* __restrict__ out,
                                              const float* __restrict__ att_s,
                                              const float* __restrict__ att_d,
                                              float* __restrict__ asrc,
                                              float* __restrict__ adst, int nrows) {
    __shared__ float Ws[FDIM * FDIM];
    __shared__ float sAs[FDIM], sAd[FDIM];
    int t = threadIdx.x;
    for (int f = t; f < FDIM * FDIM / 4; f += 256)
        ((float4*)Ws)[f] = ((const float4*)W)[f];
    if (t < FDIM) { sAs[t] = att_s[t]; sAd[t] = att_d[t]; }
    __syncthreads();

    int tx = t & 31;       // cols tx*4 .. tx*4+3
    int ty = t >> 5;       // rows ty*8 .. ty*8+7
    int row0 = blockIdx.x * 64 + ty * 8;

    float acc[8][4];
#pragma unroll
    for (int i = 0; i < 8; ++i)
#pragma unroll
        for (int j = 0; j < 4; ++j) acc[i][j] = 0.f;

    int rr[8];
#pragma unroll
    for (int i = 0; i < 8; ++i)
        rr[i] = (row0 + i < nrows) ? (row0 + i) : (nrows - 1);

#pragma unroll 2
    for (int k4 = 0; k4 < FDIM; k4 += 4) {
        float4 xv[8];
#pragma unroll
        for (int i = 0; i < 8; ++i)
            xv[i] = *(const float4*)(A + (size_t)rr[i] * FDIM + k4);
#pragma unroll
        for (int q = 0; q < 4; ++q) {
            float4 wv = *(float4*)&Ws[(k4 + q) * FDIM + tx * 4];
#pragma unroll
            for (int i = 0; i < 8; ++i) {
                float xs = (q == 0) ? xv[i].x : (q == 1) ? xv[i].y : (q == 2) ? xv[i].z : xv[i].w;
                acc[i][0] = fmaf(xs, wv.x, acc[i][0]);
                acc[i][1] = fmaf(xs, wv.y, acc[i][1]);
                acc[i][2] = fmaf(xs, wv.z, acc[i][2]);
                acc[i][3] = fmaf(xs, wv.w, acc[i][3]);
            }
        }
    }
#pragma unroll
    for (int i = 0; i < 8; ++i) {
        if (row0 + i < nrows)
            *(float4*)(out + (size_t)(row0 + i) * FDIM + tx * 4) =
                make_float4(acc[i][0], acc[i][1], acc[i][2], acc[i][3]);
    }

    // fused attention scalars: reduce acc over the 16-lane tx half-groups
    float ps[8], pd[8];
#pragma unroll
    for (int i = 0; i < 8; ++i) {
        float s = 0.f, d = 0.f;
#pragma unroll
        for (int j = 0; j < 4; ++j) {
            s = fmaf(acc[i][j], sAs[tx * 4 + j], s);
            d = fmaf(acc[i][j], sAd[tx * 4 + j], d);
        }
        ps[i] = s; pd[i] = d;
    }
#pragma unroll
    for (int off = 8; off; off >>= 1) {
#pragma unroll
        for (int i = 0; i < 8; ++i) {
            ps[i] += __shfl_xor(ps[i], off);
            pd[i] += __shfl_xor(pd[i], off);
        }
    }
    if ((tx & 15) == 0) {
        int head = tx >> 4;
#pragma unroll
        for (int i = 0; i < 8; ++i) {
            if (row0 + i < nrows) {
                asrc[2 * (row0 + i) + head] = ps[i];
                adst[2 * (row0 + i) + head] = pd[i];
            }
        }
    }
}

// ---------------- per-dst softmax + aggregation: one block (4 waves) per node ----------------

__global__ __launch_bounds__(256) void k_aggregate(const float* __restrict__ h,
                                                   const float* __restrict__ asrc,
                                                   const float* __restrict__ adst,
                                                   const int* __restrict__ rowp,
                                                   const int* __restrict__ col,
                                                   const float* __restrict__ bias,
                                                   float* __restrict__ outbuf,
                                                   const float* __restrict__ fcW,
                                                   const float* __restrict__ fcb,
                                                   float* __restrict__ outfin, int n) {
    __shared__ int    scol[256];
    __shared__ float2 sval[256];
    __shared__ float2 salpha[256];
    __shared__ float4 sredv[4];
    __shared__ float  sred[8];
    __shared__ float2 sacc[4][64];

    int node = blockIdx.x;
    if (node >= n) return;
    int t = threadIdx.x;
    int w = t >> 6;
    int lane = t & 63;
    int start = rowp[node];
    int deg = rowp[node + 1] - start;
    float2 adv = *(const float2*)(adst + 2 * node);
    float ad0 = adv.x, ad1 = adv.y;

    float m0, m1, inv0, inv1;
    int cnt;

    if (deg <= 256) {
        // ---- single pass: load edge, compute v, online max+sum ----
        float v0 = -1e30f, v1 = -1e30f;
        float s0 = 0.f, s1 = 0.f;
        if (t < deg) {
            int s = col[start + t];
            scol[t] = s;
            float2 av = *(const float2*)(asrc + 2 * s);
            v0 = lrelu(av.x + ad0);
            v1 = lrelu(av.y + ad1);
            s0 = 1.f; s1 = 1.f;
        }
        sval[t] = make_float2(v0, v1);
        m0 = v0; m1 = v1;
#pragma unroll
        for (int off = 32; off; off >>= 1) {
            float om0 = __shfl_xor(m0, off), os0 = __shfl_xor(s0, off);
            float om1 = __shfl_xor(m1, off), os1 = __shfl_xor(s1, off);
            float nm0 = fmaxf(m0, om0);
            s0 = s0 * __expf(m0 - nm0) + os0 * __expf(om0 - nm0); m0 = nm0;
            float nm1 = fmaxf(m1, om1);
            s1 = s1 * __expf(m1 - nm1) + os1 * __expf(om1 - nm1); m1 = nm1;
        }
        if (lane == 0) sredv[w] = make_float4(m0, s0, m1, s1);
        __syncthreads();
        // merge 4 waves (every thread, identical result)
        float4 r = sredv[0];
        m0 = r.x; s0 = r.y; m1 = r.z; s1 = r.w;
#pragma unroll
        for (int q = 1; q < 4; ++q) {
            float4 rq = sredv[q];
            float nm0 = fmaxf(m0, rq.x);
            s0 = s0 * __expf(m0 - nm0) + rq.y * __expf(rq.x - nm0); m0 = nm0;
            float nm1 = fmaxf(m1, rq.z);
            s1 = s1 * __expf(m1 - nm1) + rq.w * __expf(rq.z - nm1); m1 = nm1;
        }
        inv0 = 1.f / (s0 + 1e-16f);
        inv1 = 1.f / (s1 + 1e-16f);
        if (t < deg) {
            float2 v = sval[t];
            salpha[t] = make_float2(__expf(v.x - m0) * inv0, __expf(v.y - m1) * inv1);
        }
        __syncthreads();
        cnt = deg;

        // ---- gather: 4-way wave split, 2x unrolled ----
        float2 acc = make_float2(0.f, 0.f);
        float2 acc2 = make_float2(0.f, 0.f);
        int i = w;
        for (; i + 4 < cnt; i += 8) {
            int sa = scol[i], sb = scol[i + 4];
            float2 ala = salpha[i], alb = salpha[i + 4];
            float aa = (lane < 32) ? ala.x : ala.y;
            float ab = (lane < 32) ? alb.x : alb.y;
            float2 ha = *(const float2*)(h + (size_t)sa * FDIM + 2 * lane);
            float2 hb = *(const float2*)(h + (size_t)sb * FDIM + 2 * lane);
            acc.x = fmaf(ha.x, aa, acc.x);
            acc.y = fmaf(ha.y, aa, acc.y);
            acc2.x = fmaf(hb.x, ab, acc2.x);
            acc2.y = fmaf(hb.y, ab, acc2.y);
        }
        for (; i < cnt; i += 4) {
            int s = scol[i];
            float2 al = salpha[i];
            float a = (lane < 32) ? al.x : al.y;
            float2 hv = *(const float2*)(h + (size_t)s * FDIM + 2 * lane);
            acc.x = fmaf(hv.x, a, acc.x);
            acc.y = fmaf(hv.y, a, acc.y);
        }
        acc.x += acc2.x; acc.y += acc2.y;
        sacc[w][lane] = acc;
    } else {
        // ---- fallback: 3-pass chunked (deg > 256) ----
        m0 = -1e30f; m1 = -1e30f;
        for (int i2 = t; i2 < deg; i2 += 256) {
            int s = col[start + i2];
            float2 av = *(const float2*)(asrc + 2 * s);
            m0 = fmaxf(m0, lrelu(av.x + ad0));
            m1 = fmaxf(m1, lrelu(av.y + ad1));
        }
#pragma unroll
        for (int off = 32; off; off >>= 1) {
            m0 = fmaxf(m0, __shfl_xor(m0, off));
            m1 = fmaxf(m1, __shfl_xor(m1, off));
        }
        if (lane == 0) { sred[w] = m0; sred[4 + w] = m1; }
        __syncthreads();
        m0 = fmaxf(fmaxf(sred[0], sred[1]), fmaxf(sred[2], sred[3]));
        m1 = fmaxf(fmaxf(sred[4], sred[5]), fmaxf(sred[6], sred[7]));
        __syncthreads();
        float s0 = 0.f, s1 = 0.f;
        for (int i2 = t; i2 < deg; i2 += 256) {
            int s = col[start + i2];
            float2 av = *(const float2*)(asrc + 2 * s);
            s0 += __expf(lrelu(av.x + ad0) - m0);
            s1 += __expf(lrelu(av.y + ad1) - m1);
        }
#pragma unroll
        for (int off = 32; off; off >>= 1) {
            s0 += __shfl_xor(s0, off);
            s1 += __shfl_xor(s1, off);
        }
        if (lane == 0) { sred[w] = s0; sred[4 + w] = s1; }
        __syncthreads();
        inv0 = 1.f / (sred[0] + sred[1] + sred[2] + sred[3] + 1e-16f);
        inv1 = 1.f / (sred[4] + sred[5] + sred[6] + sred[7] + 1e-16f);
        __syncthreads();

        float2 acc = make_float2(0.f, 0.f);
        for (int base = 0; base < deg; base += 256) {
            int c = min(256, deg - base);
            if (t < c) {
                int s = col[start + base + t];
                scol[t] = s;
                float2 av = *(const float2*)(asrc + 2 * s);
                salpha[t] = make_float2(
                    __expf(lrelu(av.x + ad0) - m0) * inv0,
                    __expf(lrelu(av.y + ad1) - m1) * inv1);
            }
            __syncthreads();
            for (int i2 = w; i2 < c; i2 += 4) {
                int s = scol[i2];
                float2 al = salpha[i2];
                float a = (lane < 32) ? al.x : al.y;
                float2 hv = *(const float2*)(h + (size_t)s * FDIM + 2 * lane);
                acc.x = fmaf(hv.x, a, acc.x);
                acc.y = fmaf(hv.y, a, acc.y);
            }
            __syncthreads();
        }
        sacc[w][lane] = acc;
    }

    __syncthreads();
    if (w == 0) {
        float ax = sacc[0][lane].x + sacc[1][lane].x + sacc[2][lane].x + sacc[3][lane].x;
        float ay = sacc[0][lane].y + sacc[1][lane].y + sacc[2][lane].y + sacc[3][lane].y;
        int c0 = 2 * lane, c1 = 2 * lane + 1;
        float o0 = fmaxf(ax + bias[c0], 0.f);
        float o1 = fmaxf(ay + bias[c1], 0.f);
        if (outbuf)
            *(float2*)(outbuf + (size_t)node * FDIM + c0) = make_float2(o0, o1);
        if (outfin) {
            float p = fmaf(o0, fcW[c0], o1 * fcW[c1]);
#pragma unroll
            for (int off = 32; off; off >>= 1) p += __shfl_xor(p, off);
            if (lane == 0) outfin[node] = 1.f / (1.f + __expf(-(p + fcb[0])));
        }
    }
}

// ---------------- host ----------------

static inline size_t rnd256(size_t x) { return (x + 255) & ~(size_t)255; }

extern "C" void kernel_launch(void* const* d_in, const int* in_sizes, int n_in,
                              void* d_out, int out_size, void* d_ws, size_t ws_size,
                              hipStream_t stream) {
    const float* x    = (const float*)d_in[0];
    const int*   ei   = (const int*)d_in[1];
    const float* W1   = (const float*)d_in[3];
    const float* as1  = (const float*)d_in[4];
    const float* ad1  = (const float*)d_in[5];
    const float* b1   = (const float*)d_in[6];
    const float* W2   = (const float*)d_in[7];
    const float* as2  = (const float*)d_in[8];
    const float* ad2  = (const float*)d_in[9];
    const float* b2   = (const float*)d_in[10];
    const float* fcW  = (const float*)d_in[11];
    const float* fcb  = (const float*)d_in[12];

    int N = in_sizes[0] / FDIM;
    int E = in_sizes[2];
    int E2 = E + N;
    const int* srcp = ei;
    const int* dstp = ei + E;

    // workspace layout (256B-aligned regions)
    char* w = (char*)d_ws;
    float* hbuf = (float*)w;  w += rnd256((size_t)N * FDIM * sizeof(float));
    float* obuf = (float*)w;  w += rnd256((size_t)N * FDIM * sizeof(float));
    float* asrc = (float*)w;  w += rnd256((size_t)N * 2 * sizeof(float));
    float* adst = (float*)w;  w += rnd256((size_t)N * 2 * sizeof(float));
    int* rowp = (int*)w;      w += rnd256((size_t)(N + 1) * sizeof(int));
    int* deg  = (int*)w;      w += rnd256((size_t)N * sizeof(int));
    int* cnt  = (int*)w;      w += rnd256((size_t)N * sizeof(int));
    int* bsum = (int*)w;      w += rnd256((size_t)256 * sizeof(int));
    int* col  = (int*)w;      w += rnd256((size_t)E2 * sizeof(int));

    int egrid = (E2 + 255) / 256;
    int ggrid = (N + 63) / 64;
    int nblk = (N + 1023) / 1024;

    // CSR build (shared by both layers)
    hipMemsetAsync(deg, 0, (size_t)N * sizeof(int), stream);
    hipMemsetAsync(cnt, 0, (size_t)N * sizeof(int), stream);
    k_hist<<<egrid, 256, 0, stream>>>(dstp, E, N, deg);
    k_scan_local<<<nblk, 256, 0, stream>>>(deg, rowp, bsum, N);
    k_scan_mid<<<1, 64, 0, stream>>>(bsum, nblk);
    k_scan_add<<<(N + 256) / 256, 256, 0, stream>>>(bsum, rowp, N);
    k_scatter<<<egrid, 256, 0, stream>>>(srcp, dstp, E, N, rowp, cnt, col);

    // layer 1 (gemm + fused att scalars)
    k_gemm<<<ggrid, 256, 0, stream>>>(x, W1, hbuf, as1, ad1, asrc, adst, N);
    k_aggregate<<<N, 256, 0, stream>>>(hbuf, asrc, adst, rowp, col, b1,
                                       obuf, nullptr, nullptr, nullptr, N);

    // layer 2 (fc + sigmoid fused into epilogue)
    k_gemm<<<ggrid, 256, 0, stream>>>(obuf, W2, hbuf, as2, ad2, asrc, adst, N);
    k_aggregate<<<N, 256, 0, stream>>>(hbuf, asrc, adst, rowp, col, b2,
                                       nullptr, fcW, fcb, (float*)d_out, N);
}

// Round 4
// 452.116 us; speedup vs baseline: 1.7073x; 1.1718x over previous
//
#include <hip/hip_runtime.h>
#include <math.h>

#define FDIM 128
#define NEG_SLOPE 0.2f

__device__ __forceinline__ float lrelu(float x) {
    return x > 0.f ? x : NEG_SLOPE * x;
}

// ---------------- CSR build ----------------
// pass 1: rank[e] = atomicAdd(&cnt[dst],1)  (cnt doubles as histogram)
// scan(cnt) -> rowp ; pass 2: col[rowp[dst]+rank[e]] = src  (no atomics)

__global__ __launch_bounds__(256) void k_rank(const int* __restrict__ dstp,
                                              int E, int N,
                                              int* __restrict__ cnt,
                                              unsigned short* __restrict__ rank) {
    int e = blockIdx.x * 256 + threadIdx.x;
    int total = E + N;
    if (e >= total) return;
    int d = (e < E) ? dstp[e] : (e - E);
    rank[e] = (unsigned short)atomicAdd(&cnt[d], 1);
}

__global__ __launch_bounds__(256) void k_scan_local(const int* __restrict__ deg,
                                                    int* __restrict__ rowp,
                                                    int* __restrict__ bsum, int n) {
    __shared__ int sh[256];
    int b = blockIdx.x, t = threadIdx.x;
    int base = b * 1024 + t * 4;
    int4 v = make_int4(0, 0, 0, 0);
    if (base + 3 < n) v = *(const int4*)(deg + base);
    else {
        if (base < n)     v.x = deg[base];
        if (base + 1 < n) v.y = deg[base + 1];
        if (base + 2 < n) v.z = deg[base + 2];
        if (base + 3 < n) v.w = deg[base + 3];
    }
    int s = v.x + v.y + v.z + v.w;
    sh[t] = s;
    __syncthreads();
    for (int off = 1; off < 256; off <<= 1) {
        int u = (t >= off) ? sh[t - off] : 0;
        __syncthreads();
        sh[t] += u;
        __syncthreads();
    }
    int excl = t ? sh[t - 1] : 0;
    int r0 = excl + v.x, r1 = r0 + v.y, r2 = r1 + v.z, r3 = r2 + v.w;
    if (base < n)     rowp[base + 1] = r0;
    if (base + 1 < n) rowp[base + 2] = r1;
    if (base + 2 < n) rowp[base + 3] = r2;
    if (base + 3 < n) rowp[base + 4] = r3;
    if (t == 255) bsum[b] = sh[255];
}

__global__ void k_scan_mid(int* __restrict__ bsum, int nb) {
    int lane = threadIdx.x;
    int own = (lane < nb) ? bsum[lane] : 0;
    int v = own;
    for (int off = 1; off < 64; off <<= 1) {
        int u = __shfl(v, lane - off);
        if (lane >= off) v += u;
    }
    if (lane < nb) bsum[lane] = v - own;  // exclusive
}

__global__ __launch_bounds__(256) void k_scan_add(const int* __restrict__ bsum,
                                                  int* __restrict__ rowp, int n) {
    int idx = blockIdx.x * 256 + threadIdx.x;
    if (idx > n) return;
    if (idx == 0) { rowp[0] = 0; return; }
    int blk = (idx - 1) >> 10;
    if (blk > 0) rowp[idx] += bsum[blk];
}

__global__ __launch_bounds__(256) void k_place(const int* __restrict__ srcp,
                                               const int* __restrict__ dstp,
                                               int E, int N,
                                               const int* __restrict__ rowp,
                                               const unsigned short* __restrict__ rank,
                                               int* __restrict__ col) {
    int e = blockIdx.x * 256 + threadIdx.x;
    int total = E + N;
    if (e >= total) return;
    int s, d;
    if (e < E) { s = srcp[e]; d = dstp[e]; }
    else       { s = d = e - E; }
    col[rowp[d] + rank[e]] = s;
}

// ---------------- GEMM (+ fused attention scalars): 64 rows/block ----------------

__global__ __launch_bounds__(256) void k_gemm(const float* __restrict__ A,
                                              const float* __restrict__ W,
                                              float* __restrict__ out,
                                              const float* __restrict__ att_s,
                                              const float* __restrict__ att_d,
                                              float* __restrict__ asrc,
                                              float* __restrict__ adst, int nrows) {
    __shared__ float Ws[FDIM * FDIM];
    __shared__ float sAs[FDIM], sAd[FDIM];
    int t = threadIdx.x;
    for (int f = t; f < FDIM * FDIM / 4; f += 256)
        ((float4*)Ws)[f] = ((const float4*)W)[f];
    if (t < FDIM) { sAs[t] = att_s[t]; sAd[t] = att_d[t]; }
    __syncthreads();

    int tx = t & 31;
    int ty = t >> 5;
    int row0 = blockIdx.x * 64 + ty * 8;

    float acc[8][4];
#pragma unroll
    for (int i = 0; i < 8; ++i)
#pragma unroll
        for (int j = 0; j < 4; ++j) acc[i][j] = 0.f;

    int rr[8];
#pragma unroll
    for (int i = 0; i < 8; ++i)
        rr[i] = (row0 + i < nrows) ? (row0 + i) : (nrows - 1);

#pragma unroll 2
    for (int k4 = 0; k4 < FDIM; k4 += 4) {
        float4 xv[8];
#pragma unroll
        for (int i = 0; i < 8; ++i)
            xv[i] = *(const float4*)(A + (size_t)rr[i] * FDIM + k4);
#pragma unroll
        for (int q = 0; q < 4; ++q) {
            float4 wv = *(float4*)&Ws[(k4 + q) * FDIM + tx * 4];
#pragma unroll
            for (int i = 0; i < 8; ++i) {
                float xs = (q == 0) ? xv[i].x : (q == 1) ? xv[i].y : (q == 2) ? xv[i].z : xv[i].w;
                acc[i][0] = fmaf(xs, wv.x, acc[i][0]);
                acc[i][1] = fmaf(xs, wv.y, acc[i][1]);
                acc[i][2] = fmaf(xs, wv.z, acc[i][2]);
                acc[i][3] = fmaf(xs, wv.w, acc[i][3]);
            }
        }
    }
#pragma unroll
    for (int i = 0; i < 8; ++i) {
        if (row0 + i < nrows)
            *(float4*)(out + (size_t)(row0 + i) * FDIM + tx * 4) =
                make_float4(acc[i][0], acc[i][1], acc[i][2], acc[i][3]);
    }

    float ps[8], pd[8];
#pragma unroll
    for (int i = 0; i < 8; ++i) {
        float s = 0.f, d = 0.f;
#pragma unroll
        for (int j = 0; j < 4; ++j) {
            s = fmaf(acc[i][j], sAs[tx * 4 + j], s);
            d = fmaf(acc[i][j], sAd[tx * 4 + j], d);
        }
        ps[i] = s; pd[i] = d;
    }
#pragma unroll
    for (int off = 8; off; off >>= 1) {
#pragma unroll
        for (int i = 0; i < 8; ++i) {
            ps[i] += __shfl_xor(ps[i], off);
            pd[i] += __shfl_xor(pd[i], off);
        }
    }
    if ((tx & 15) == 0) {
        int head = tx >> 4;
#pragma unroll
        for (int i = 0; i < 8; ++i) {
            if (row0 + i < nrows) {
                asrc[2 * (row0 + i) + head] = ps[i];
                adst[2 * (row0 + i) + head] = pd[i];
            }
        }
    }
}

// ---------------- per-dst softmax + aggregation: one block (4 waves) per node ----------------
// deg<=256 fast path: value-in-register 2-phase softmax (2 exps/thread),
// per-lane alpha table (no per-edge select), 32-bit gather addressing.

__global__ __launch_bounds__(256) void k_aggregate(const float* __restrict__ h,
                                                   const float* __restrict__ asrc,
                                                   const float* __restrict__ adst,
                                                   const int* __restrict__ rowp,
                                                   const int* __restrict__ col,
                                                   const float* __restrict__ bias,
                                                   float* __restrict__ outbuf,
                                                   const float* __restrict__ fcW,
                                                   const float* __restrict__ fcb,
                                                   float* __restrict__ outfin, int n) {
    __shared__ int   scol[256];
    __shared__ float sal0[256], sal1[256];
    __shared__ float sredm[8];
    __shared__ float sreds[8];
    __shared__ float2 sacc[4][64];

    int node = blockIdx.x;
    if (node >= n) return;
    int t = threadIdx.x;
    int w = t >> 6;
    int lane = t & 63;
    int start = rowp[node];
    int deg = rowp[node + 1] - start;
    float2 adv = *(const float2*)(adst + 2 * node);
    float ad0 = adv.x, ad1 = adv.y;
    const float2* __restrict__ h2 = (const float2*)h;

    if (__builtin_expect(deg <= 256, 1)) {
        // ---- load + value compute (registers) ----
        float v0 = -1e30f, v1 = -1e30f;
        if (t < deg) {
            int s = col[start + t];
            scol[t] = s;
            float2 av = *(const float2*)(asrc + 2 * s);
            v0 = lrelu(av.x + ad0);
            v1 = lrelu(av.y + ad1);
        }
        // ---- max reduce ----
        float m0 = v0, m1 = v1;
#pragma unroll
        for (int off = 32; off; off >>= 1) {
            m0 = fmaxf(m0, __shfl_xor(m0, off));
            m1 = fmaxf(m1, __shfl_xor(m1, off));
        }
        if (lane == 0) { sredm[w] = m0; sredm[4 + w] = m1; }
        __syncthreads();
        m0 = fmaxf(fmaxf(sredm[0], sredm[1]), fmaxf(sredm[2], sredm[3]));
        m1 = fmaxf(fmaxf(sredm[4], sredm[5]), fmaxf(sredm[6], sredm[7]));
        // ---- exp once + sum reduce ----
        float e0 = (t < deg) ? __expf(v0 - m0) : 0.f;
        float e1 = (t < deg) ? __expf(v1 - m1) : 0.f;
        float s0 = e0, s1 = e1;
#pragma unroll
        for (int off = 32; off; off >>= 1) {
            s0 += __shfl_xor(s0, off);
            s1 += __shfl_xor(s1, off);
        }
        if (lane == 0) { sreds[w] = s0; sreds[4 + w] = s1; }
        __syncthreads();
        float inv0 = 1.f / (sreds[0] + sreds[1] + sreds[2] + sreds[3] + 1e-16f);
        float inv1 = 1.f / (sreds[4] + sreds[5] + sreds[6] + sreds[7] + 1e-16f);
        if (t < deg) { sal0[t] = e0 * inv0; sal1[t] = e1 * inv1; }
        __syncthreads();

        // ---- gather: 4-way wave split, 2x unrolled, per-lane alpha table ----
        const float* __restrict__ amy = (lane < 32) ? sal0 : sal1;
        float2 acc = make_float2(0.f, 0.f);
        float2 acc2 = make_float2(0.f, 0.f);
        int i = w;
        for (; i + 4 < deg; i += 8) {
            unsigned sa = (unsigned)scol[i], sb = (unsigned)scol[i + 4];
            float aa = amy[i], ab = amy[i + 4];
            float2 ha = h2[sa * 64u + lane];
            float2 hb = h2[sb * 64u + lane];
            acc.x = fmaf(ha.x, aa, acc.x);
            acc.y = fmaf(ha.y, aa, acc.y);
            acc2.x = fmaf(hb.x, ab, acc2.x);
            acc2.y = fmaf(hb.y, ab, acc2.y);
        }
        for (; i < deg; i += 4) {
            unsigned s = (unsigned)scol[i];
            float a = amy[i];
            float2 hv = h2[s * 64u + lane];
            acc.x = fmaf(hv.x, a, acc.x);
            acc.y = fmaf(hv.y, a, acc.y);
        }
        acc.x += acc2.x; acc.y += acc2.y;
        sacc[w][lane] = acc;
    } else {
        // ---- fallback: 3-pass chunked (deg > 256) ----
        float m0 = -1e30f, m1 = -1e30f;
        for (int i2 = t; i2 < deg; i2 += 256) {
            int s = col[start + i2];
            float2 av = *(const float2*)(asrc + 2 * s);
            m0 = fmaxf(m0, lrelu(av.x + ad0));
            m1 = fmaxf(m1, lrelu(av.y + ad1));
        }
#pragma unroll
        for (int off = 32; off; off >>= 1) {
            m0 = fmaxf(m0, __shfl_xor(m0, off));
            m1 = fmaxf(m1, __shfl_xor(m1, off));
        }
        if (lane == 0) { sredm[w] = m0; sredm[4 + w] = m1; }
        __syncthreads();
        m0 = fmaxf(fmaxf(sredm[0], sredm[1]), fmaxf(sredm[2], sredm[3]));
        m1 = fmaxf(fmaxf(sredm[4], sredm[5]), fmaxf(sredm[6], sredm[7]));
        __syncthreads();
        float s0 = 0.f, s1 = 0.f;
        for (int i2 = t; i2 < deg; i2 += 256) {
            int s = col[start + i2];
            float2 av = *(const float2*)(asrc + 2 * s);
            s0 += __expf(lrelu(av.x + ad0) - m0);
            s1 += __expf(lrelu(av.y + ad1) - m1);
        }
#pragma unroll
        for (int off = 32; off; off >>= 1) {
            s0 += __shfl_xor(s0, off);
            s1 += __shfl_xor(s1, off);
        }
        if (lane == 0) { sreds[w] = s0; sreds[4 + w] = s1; }
        __syncthreads();
        float inv0 = 1.f / (sreds[0] + sreds[1] + sreds[2] + sreds[3] + 1e-16f);
        float inv1 = 1.f / (sreds[4] + sreds[5] + sreds[6] + sreds[7] + 1e-16f);
        __syncthreads();

        const float* __restrict__ amy = (lane < 32) ? sal0 : sal1;
        float2 acc = make_float2(0.f, 0.f);
        for (int base = 0; base < deg; base += 256) {
            int c = min(256, deg - base);
            if (t < c) {
                int s = col[start + base + t];
                scol[t] = s;
                float2 av = *(const float2*)(asrc + 2 * s);
                sal0[t] = __expf(lrelu(av.x + ad0) - m0) * inv0;
                sal1[t] = __expf(lrelu(av.y + ad1) - m1) * inv1;
            }
            __syncthreads();
            for (int i2 = w; i2 < c; i2 += 4) {
                unsigned s = (unsigned)scol[i2];
                float a = amy[i2];
                float2 hv = h2[s * 64u + lane];
                acc.x = fmaf(hv.x, a, acc.x);
                acc.y = fmaf(hv.y, a, acc.y);
            }
            __syncthreads();
        }
        sacc[w][lane] = acc;
    }

    __syncthreads();
    if (w == 0) {
        float ax = sacc[0][lane].x + sacc[1][lane].x + sacc[2][lane].x + sacc[3][lane].x;
        float ay = sacc[0][lane].y + sacc[1][lane].y + sacc[2][lane].y + sacc[3][lane].y;
        int c0 = 2 * lane, c1 = 2 * lane + 1;
        float o0 = fmaxf(ax + bias[c0], 0.f);
        float o1 = fmaxf(ay + bias[c1], 0.f);
        if (outbuf)
            *(float2*)(outbuf + (size_t)node * FDIM + c0) = make_float2(o0, o1);
        if (outfin) {
            float p = fmaf(o0, fcW[c0], o1 * fcW[c1]);
#pragma unroll
            for (int off = 32; off; off >>= 1) p += __shfl_xor(p, off);
            if (lane == 0) outfin[node] = 1.f / (1.f + __expf(-(p + fcb[0])));
        }
    }
}

// ---------------- host ----------------

static inline size_t rnd256(size_t x) { return (x + 255) & ~(size_t)255; }

extern "C" void kernel_launch(void* const* d_in, const int* in_sizes, int n_in,
                              void* d_out, int out_size, void* d_ws, size_t ws_size,
                              hipStream_t stream) {
    const float* x    = (const float*)d_in[0];
    const int*   ei   = (const int*)d_in[1];
    const float* W1   = (const float*)d_in[3];
    const float* as1  = (const float*)d_in[4];
    const float* ad1  = (const float*)d_in[5];
    const float* b1   = (const float*)d_in[6];
    const float* W2   = (const float*)d_in[7];
    const float* as2  = (const float*)d_in[8];
    const float* ad2  = (const float*)d_in[9];
    const float* b2   = (const float*)d_in[10];
    const float* fcW  = (const float*)d_in[11];
    const float* fcb  = (const float*)d_in[12];

    int N = in_sizes[0] / FDIM;
    int E = in_sizes[2];
    int E2 = E + N;
    const int* srcp = ei;
    const int* dstp = ei + E;

    char* w = (char*)d_ws;
    float* hbuf = (float*)w;  w += rnd256((size_t)N * FDIM * sizeof(float));
    float* obuf = (float*)w;  w += rnd256((size_t)N * FDIM * sizeof(float));
    float* asrc = (float*)w;  w += rnd256((size_t)N * 2 * sizeof(float));
    float* adst = (float*)w;  w += rnd256((size_t)N * 2 * sizeof(float));
    int* rowp = (int*)w;      w += rnd256((size_t)(N + 1) * sizeof(int));
    int* cnt  = (int*)w;      w += rnd256((size_t)N * sizeof(int));
    int* bsum = (int*)w;      w += rnd256((size_t)256 * sizeof(int));
    unsigned short* rank = (unsigned short*)w; w += rnd256((size_t)E2 * sizeof(unsigned short));
    int* col  = (int*)w;      w += rnd256((size_t)E2 * sizeof(int));

    int egrid = (E2 + 255) / 256;
    int ggrid = (N + 63) / 64;
    int nblk = (N + 1023) / 1024;

    // CSR build (shared by both layers)
    hipMemsetAsync(cnt, 0, (size_t)N * sizeof(int), stream);
    k_rank<<<egrid, 256, 0, stream>>>(dstp, E, N, cnt, rank);
    k_scan_local<<<nblk, 256, 0, stream>>>(cnt, rowp, bsum, N);
    k_scan_mid<<<1, 64, 0, stream>>>(bsum, nblk);
    k_scan_add<<<(N + 256) / 256, 256, 0, stream>>>(bsum, rowp, N);
    k_place<<<egrid, 256, 0, stream>>>(srcp, dstp, E, N, rowp, rank, col);

    // layer 1 (gemm + fused att scalars)
    k_gemm<<<ggrid, 256, 0, stream>>>(x, W1, hbuf, as1, ad1, asrc, adst, N);
    k_aggregate<<<N, 256, 0, stream>>>(hbuf, asrc, adst, rowp, col, b1,
                                       obuf, nullptr, nullptr, nullptr, N);

    // layer 2 (fc + sigmoid fused into epilogue)
    k_gemm<<<ggrid, 256, 0, stream>>>(obuf, W2, hbuf, as2, ad2, asrc, adst, N);
    k_aggregate<<<N, 256, 0, stream>>>(hbuf, asrc, adst, rowp, col, b2,
                                       nullptr, fcW, fcb, (float*)d_out, N);
}

// Round 5
// 396.024 us; speedup vs baseline: 1.9491x; 1.1416x over previous
//
#include <hip/hip_runtime.h>
#include <math.h>

#define FDIM 128
#define NEG_SLOPE 0.2f

__device__ __forceinline__ float lrelu(float x) {
    return x > 0.f ? x : NEG_SLOPE * x;
}

// bf16 helpers (RNE; inputs finite)
__device__ __forceinline__ unsigned short f2bf(float f) {
    unsigned u = __float_as_uint(f);
    return (unsigned short)((u + 0x7FFFu + ((u >> 16) & 1u)) >> 16);
}
__device__ __forceinline__ float bf2f(unsigned short h) {
    return __uint_as_float((unsigned)h << 16);
}

// ---------------- CSR build ----------------
// pass 1: rank[e] = atomicAdd(&cnt[dst],1)  (cnt doubles as histogram)
// scan(cnt) -> rowp ; pass 2: col[rowp[dst]+rank[e]] = src  (no atomics)

__global__ __launch_bounds__(256) void k_rank(const int* __restrict__ dstp,
                                              int E, int N,
                                              int* __restrict__ cnt,
                                              unsigned short* __restrict__ rank) {
    int e = blockIdx.x * 256 + threadIdx.x;
    int total = E + N;
    if (e >= total) return;
    int d = (e < E) ? dstp[e] : (e - E);
    rank[e] = (unsigned short)atomicAdd(&cnt[d], 1);
}

__global__ __launch_bounds__(256) void k_scan_local(const int* __restrict__ deg,
                                                    int* __restrict__ rowp,
                                                    int* __restrict__ bsum, int n) {
    __shared__ int sh[256];
    int b = blockIdx.x, t = threadIdx.x;
    int base = b * 1024 + t * 4;
    int4 v = make_int4(0, 0, 0, 0);
    if (base + 3 < n) v = *(const int4*)(deg + base);
    else {
        if (base < n)     v.x = deg[base];
        if (base + 1 < n) v.y = deg[base + 1];
        if (base + 2 < n) v.z = deg[base + 2];
        if (base + 3 < n) v.w = deg[base + 3];
    }
    int s = v.x + v.y + v.z + v.w;
    sh[t] = s;
    __syncthreads();
    for (int off = 1; off < 256; off <<= 1) {
        int u = (t >= off) ? sh[t - off] : 0;
        __syncthreads();
        sh[t] += u;
        __syncthreads();
    }
    int excl = t ? sh[t - 1] : 0;
    int r0 = excl + v.x, r1 = r0 + v.y, r2 = r1 + v.z, r3 = r2 + v.w;
    if (base < n)     rowp[base + 1] = r0;
    if (base + 1 < n) rowp[base + 2] = r1;
    if (base + 2 < n) rowp[base + 3] = r2;
    if (base + 3 < n) rowp[base + 4] = r3;
    if (t == 255) bsum[b] = sh[255];
}

__global__ void k_scan_mid(int* __restrict__ bsum, int nb) {
    int lane = threadIdx.x;
    int own = (lane < nb) ? bsum[lane] : 0;
    int v = own;
    for (int off = 1; off < 64; off <<= 1) {
        int u = __shfl(v, lane - off);
        if (lane >= off) v += u;
    }
    if (lane < nb) bsum[lane] = v - own;  // exclusive
}

__global__ __launch_bounds__(256) void k_scan_add(const int* __restrict__ bsum,
                                                  int* __restrict__ rowp, int n) {
    int idx = blockIdx.x * 256 + threadIdx.x;
    if (idx > n) return;
    if (idx == 0) { rowp[0] = 0; return; }
    int blk = (idx - 1) >> 10;
    if (blk > 0) rowp[idx] += bsum[blk];
}

__global__ __launch_bounds__(256) void k_place(const int* __restrict__ srcp,
                                               const int* __restrict__ dstp,
                                               int E, int N,
                                               const int* __restrict__ rowp,
                                               const unsigned short* __restrict__ rank,
                                               int* __restrict__ col) {
    int e = blockIdx.x * 256 + threadIdx.x;
    int total = E + N;
    if (e >= total) return;
    int s, d;
    if (e < E) { s = srcp[e]; d = dstp[e]; }
    else       { s = d = e - E; }
    col[rowp[d] + rank[e]] = s;
}

// ---------------- GEMM (+ fused attention scalars): 64 rows/block ----------------
// Writes the GEMM result as bf16 (consumed only by the aggregate gather).
// Attention scalars computed from the f32 accumulators.

__global__ __launch_bounds__(256) void k_gemm(const float* __restrict__ A,
                                              const float* __restrict__ W,
                                              unsigned short* __restrict__ out,
                                              const float* __restrict__ att_s,
                                              const float* __restrict__ att_d,
                                              float* __restrict__ asrc,
                                              float* __restrict__ adst, int nrows) {
    __shared__ float Ws[FDIM * FDIM];
    __shared__ float sAs[FDIM], sAd[FDIM];
    int t = threadIdx.x;
    for (int f = t; f < FDIM * FDIM / 4; f += 256)
        ((float4*)Ws)[f] = ((const float4*)W)[f];
    if (t < FDIM) { sAs[t] = att_s[t]; sAd[t] = att_d[t]; }
    __syncthreads();

    int tx = t & 31;
    int ty = t >> 5;
    int row0 = blockIdx.x * 64 + ty * 8;

    float acc[8][4];
#pragma unroll
    for (int i = 0; i < 8; ++i)
#pragma unroll
        for (int j = 0; j < 4; ++j) acc[i][j] = 0.f;

    int rr[8];
#pragma unroll
    for (int i = 0; i < 8; ++i)
        rr[i] = (row0 + i < nrows) ? (row0 + i) : (nrows - 1);

#pragma unroll 2
    for (int k4 = 0; k4 < FDIM; k4 += 4) {
        float4 xv[8];
#pragma unroll
        for (int i = 0; i < 8; ++i)
            xv[i] = *(const float4*)(A + (size_t)rr[i] * FDIM + k4);
#pragma unroll
        for (int q = 0; q < 4; ++q) {
            float4 wv = *(float4*)&Ws[(k4 + q) * FDIM + tx * 4];
#pragma unroll
            for (int i = 0; i < 8; ++i) {
                float xs = (q == 0) ? xv[i].x : (q == 1) ? xv[i].y : (q == 2) ? xv[i].z : xv[i].w;
                acc[i][0] = fmaf(xs, wv.x, acc[i][0]);
                acc[i][1] = fmaf(xs, wv.y, acc[i][1]);
                acc[i][2] = fmaf(xs, wv.z, acc[i][2]);
                acc[i][3] = fmaf(xs, wv.w, acc[i][3]);
            }
        }
    }
#pragma unroll
    for (int i = 0; i < 8; ++i) {
        if (row0 + i < nrows) {
            ushort4 o;
            o.x = f2bf(acc[i][0]);
            o.y = f2bf(acc[i][1]);
            o.z = f2bf(acc[i][2]);
            o.w = f2bf(acc[i][3]);
            *(ushort4*)(out + (size_t)(row0 + i) * FDIM + tx * 4) = o;
        }
    }

    float ps[8], pd[8];
#pragma unroll
    for (int i = 0; i < 8; ++i) {
        float s = 0.f, d = 0.f;
#pragma unroll
        for (int j = 0; j < 4; ++j) {
            s = fmaf(acc[i][j], sAs[tx * 4 + j], s);
            d = fmaf(acc[i][j], sAd[tx * 4 + j], d);
        }
        ps[i] = s; pd[i] = d;
    }
#pragma unroll
    for (int off = 8; off; off >>= 1) {
#pragma unroll
        for (int i = 0; i < 8; ++i) {
            ps[i] += __shfl_xor(ps[i], off);
            pd[i] += __shfl_xor(pd[i], off);
        }
    }
    if ((tx & 15) == 0) {
        int head = tx >> 4;
#pragma unroll
        for (int i = 0; i < 8; ++i) {
            if (row0 + i < nrows) {
                asrc[2 * (row0 + i) + head] = ps[i];
                adst[2 * (row0 + i) + head] = pd[i];
            }
        }
    }
}

// ---------------- per-dst softmax + aggregation: one block (4 waves) per node ----------------
// h is bf16 [N][128]; lane holds channels 2*lane, 2*lane+1 (ushort2 = 4B/lane, 256B/wave/edge).
// Gather: 4-way wave split with 4 independent accumulator chains.

__global__ __launch_bounds__(256) void k_aggregate(const unsigned short* __restrict__ h,
                                                   const float* __restrict__ asrc,
                                                   const float* __restrict__ adst,
                                                   const int* __restrict__ rowp,
                                                   const int* __restrict__ col,
                                                   const float* __restrict__ bias,
                                                   float* __restrict__ outbuf,
                                                   const float* __restrict__ fcW,
                                                   const float* __restrict__ fcb,
                                                   float* __restrict__ outfin, int n) {
    __shared__ int   scol[256];
    __shared__ float sal0[256], sal1[256];
    __shared__ float sredm[8];
    __shared__ float sreds[8];
    __shared__ float2 sacc[4][64];

    int node = blockIdx.x;
    if (node >= n) return;
    int t = threadIdx.x;
    int w = t >> 6;
    int lane = t & 63;
    int start = rowp[node];
    int deg = rowp[node + 1] - start;
    float2 adv = *(const float2*)(adst + 2 * node);
    float ad0 = adv.x, ad1 = adv.y;
    const ushort2* __restrict__ hb = (const ushort2*)h;

    if (__builtin_expect(deg <= 256, 1)) {
        // ---- load + value compute (registers) ----
        float v0 = -1e30f, v1 = -1e30f;
        if (t < deg) {
            int s = col[start + t];
            scol[t] = s;
            float2 av = *(const float2*)(asrc + 2 * s);
            v0 = lrelu(av.x + ad0);
            v1 = lrelu(av.y + ad1);
        }
        // ---- max reduce ----
        float m0 = v0, m1 = v1;
#pragma unroll
        for (int off = 32; off; off >>= 1) {
            m0 = fmaxf(m0, __shfl_xor(m0, off));
            m1 = fmaxf(m1, __shfl_xor(m1, off));
        }
        if (lane == 0) { sredm[w] = m0; sredm[4 + w] = m1; }
        __syncthreads();
        m0 = fmaxf(fmaxf(sredm[0], sredm[1]), fmaxf(sredm[2], sredm[3]));
        m1 = fmaxf(fmaxf(sredm[4], sredm[5]), fmaxf(sredm[6], sredm[7]));
        // ---- exp once + sum reduce ----
        float e0 = (t < deg) ? __expf(v0 - m0) : 0.f;
        float e1 = (t < deg) ? __expf(v1 - m1) : 0.f;
        float s0 = e0, s1 = e1;
#pragma unroll
        for (int off = 32; off; off >>= 1) {
            s0 += __shfl_xor(s0, off);
            s1 += __shfl_xor(s1, off);
        }
        if (lane == 0) { sreds[w] = s0; sreds[4 + w] = s1; }
        __syncthreads();
        float inv0 = 1.f / (sreds[0] + sreds[1] + sreds[2] + sreds[3] + 1e-16f);
        float inv1 = 1.f / (sreds[4] + sreds[5] + sreds[6] + sreds[7] + 1e-16f);
        if (t < deg) { sal0[t] = e0 * inv0; sal1[t] = e1 * inv1; }
        __syncthreads();

        // ---- gather: 4-way wave split, 4 independent chains ----
        const float* __restrict__ amy = (lane < 32) ? sal0 : sal1;
        float2 a0 = make_float2(0.f, 0.f), a1 = make_float2(0.f, 0.f);
        float2 a2 = make_float2(0.f, 0.f), a3 = make_float2(0.f, 0.f);
        int i = w;
        for (; i + 12 < deg; i += 16) {
            unsigned sa = (unsigned)scol[i],      sb = (unsigned)scol[i + 4];
            unsigned sc = (unsigned)scol[i + 8],  sd = (unsigned)scol[i + 12];
            float wa = amy[i], wb = amy[i + 4], wc = amy[i + 8], wd = amy[i + 12];
            ushort2 ha = hb[sa * 64u + lane];
            ushort2 hbv = hb[sb * 64u + lane];
            ushort2 hc = hb[sc * 64u + lane];
            ushort2 hd = hb[sd * 64u + lane];
            a0.x = fmaf(bf2f(ha.x), wa, a0.x);  a0.y = fmaf(bf2f(ha.y), wa, a0.y);
            a1.x = fmaf(bf2f(hbv.x), wb, a1.x); a1.y = fmaf(bf2f(hbv.y), wb, a1.y);
            a2.x = fmaf(bf2f(hc.x), wc, a2.x);  a2.y = fmaf(bf2f(hc.y), wc, a2.y);
            a3.x = fmaf(bf2f(hd.x), wd, a3.x);  a3.y = fmaf(bf2f(hd.y), wd, a3.y);
        }
        for (; i < deg; i += 4) {
            unsigned s = (unsigned)scol[i];
            float a = amy[i];
            ushort2 hv = hb[s * 64u + lane];
            a0.x = fmaf(bf2f(hv.x), a, a0.x);
            a0.y = fmaf(bf2f(hv.y), a, a0.y);
        }
        a0.x += a1.x + a2.x + a3.x;
        a0.y += a1.y + a2.y + a3.y;
        sacc[w][lane] = a0;
    } else {
        // ---- fallback: 3-pass chunked (deg > 256) ----
        float m0 = -1e30f, m1 = -1e30f;
        for (int i2 = t; i2 < deg; i2 += 256) {
            int s = col[start + i2];
            float2 av = *(const float2*)(asrc + 2 * s);
            m0 = fmaxf(m0, lrelu(av.x + ad0));
            m1 = fmaxf(m1, lrelu(av.y + ad1));
        }
#pragma unroll
        for (int off = 32; off; off >>= 1) {
            m0 = fmaxf(m0, __shfl_xor(m0, off));
            m1 = fmaxf(m1, __shfl_xor(m1, off));
        }
        if (lane == 0) { sredm[w] = m0; sredm[4 + w] = m1; }
        __syncthreads();
        m0 = fmaxf(fmaxf(sredm[0], sredm[1]), fmaxf(sredm[2], sredm[3]));
        m1 = fmaxf(fmaxf(sredm[4], sredm[5]), fmaxf(sredm[6], sredm[7]));
        __syncthreads();
        float s0 = 0.f, s1 = 0.f;
        for (int i2 = t; i2 < deg; i2 += 256) {
            int s = col[start + i2];
            float2 av = *(const float2*)(asrc + 2 * s);
            s0 += __expf(lrelu(av.x + ad0) - m0);
            s1 += __expf(lrelu(av.y + ad1) - m1);
        }
#pragma unroll
        for (int off = 32; off; off >>= 1) {
            s0 += __shfl_xor(s0, off);
            s1 += __shfl_xor(s1, off);
        }
        if (lane == 0) { sreds[w] = s0; sreds[4 + w] = s1; }
        __syncthreads();
        float inv0 = 1.f / (sreds[0] + sreds[1] + sreds[2] + sreds[3] + 1e-16f);
        float inv1 = 1.f / (sreds[4] + sreds[5] + sreds[6] + sreds[7] + 1e-16f);
        __syncthreads();

        const float* __restrict__ amy = (lane < 32) ? sal0 : sal1;
        float2 acc = make_float2(0.f, 0.f);
        for (int base = 0; base < deg; base += 256) {
            int c = min(256, deg - base);
            if (t < c) {
                int s = col[start + base + t];
                scol[t] = s;
                float2 av = *(const float2*)(asrc + 2 * s);
                sal0[t] = __expf(lrelu(av.x + ad0) - m0) * inv0;
                sal1[t] = __expf(lrelu(av.y + ad1) - m1) * inv1;
            }
            __syncthreads();
            for (int i2 = w; i2 < c; i2 += 4) {
                unsigned s = (unsigned)scol[i2];
                float a = amy[i2];
                ushort2 hv = hb[s * 64u + lane];
                acc.x = fmaf(bf2f(hv.x), a, acc.x);
                acc.y = fmaf(bf2f(hv.y), a, acc.y);
            }
            __syncthreads();
        }
        sacc[w][lane] = acc;
    }

    __syncthreads();
    if (w == 0) {
        float ax = sacc[0][lane].x + sacc[1][lane].x + sacc[2][lane].x + sacc[3][lane].x;
        float ay = sacc[0][lane].y + sacc[1][lane].y + sacc[2][lane].y + sacc[3][lane].y;
        int c0 = 2 * lane, c1 = 2 * lane + 1;
        float o0 = fmaxf(ax + bias[c0], 0.f);
        float o1 = fmaxf(ay + bias[c1], 0.f);
        if (outbuf)
            *(float2*)(outbuf + (size_t)node * FDIM + c0) = make_float2(o0, o1);
        if (outfin) {
            float p = fmaf(o0, fcW[c0], o1 * fcW[c1]);
#pragma unroll
            for (int off = 32; off; off >>= 1) p += __shfl_xor(p, off);
            if (lane == 0) outfin[node] = 1.f / (1.f + __expf(-(p + fcb[0])));
        }
    }
}

// ---------------- host ----------------

static inline size_t rnd256(size_t x) { return (x + 255) & ~(size_t)255; }

extern "C" void kernel_launch(void* const* d_in, const int* in_sizes, int n_in,
                              void* d_out, int out_size, void* d_ws, size_t ws_size,
                              hipStream_t stream) {
    const float* x    = (const float*)d_in[0];
    const int*   ei   = (const int*)d_in[1];
    const float* W1   = (const float*)d_in[3];
    const float* as1  = (const float*)d_in[4];
    const float* ad1  = (const float*)d_in[5];
    const float* b1   = (const float*)d_in[6];
    const float* W2   = (const float*)d_in[7];
    const float* as2  = (const float*)d_in[8];
    const float* ad2  = (const float*)d_in[9];
    const float* b2   = (const float*)d_in[10];
    const float* fcW  = (const float*)d_in[11];
    const float* fcb  = (const float*)d_in[12];

    int N = in_sizes[0] / FDIM;
    int E = in_sizes[2];
    int E2 = E + N;
    const int* srcp = ei;
    const int* dstp = ei + E;

    char* w = (char*)d_ws;
    unsigned short* hbuf = (unsigned short*)w; w += rnd256((size_t)N * FDIM * sizeof(unsigned short));
    float* obuf = (float*)w;  w += rnd256((size_t)N * FDIM * sizeof(float));
    float* asrc = (float*)w;  w += rnd256((size_t)N * 2 * sizeof(float));
    float* adst = (float*)w;  w += rnd256((size_t)N * 2 * sizeof(float));
    int* rowp = (int*)w;      w += rnd256((size_t)(N + 1) * sizeof(int));
    int* cnt  = (int*)w;      w += rnd256((size_t)N * sizeof(int));
    int* bsum = (int*)w;      w += rnd256((size_t)256 * sizeof(int));
    unsigned short* rank = (unsigned short*)w; w += rnd256((size_t)E2 * sizeof(unsigned short));
    int* col  = (int*)w;      w += rnd256((size_t)E2 * sizeof(int));

    int egrid = (E2 + 255) / 256;
    int ggrid = (N + 63) / 64;
    int nblk = (N + 1023) / 1024;

    // CSR build (shared by both layers)
    hipMemsetAsync(cnt, 0, (size_t)N * sizeof(int), stream);
    k_rank<<<egrid, 256, 0, stream>>>(dstp, E, N, cnt, rank);
    k_scan_local<<<nblk, 256, 0, stream>>>(cnt, rowp, bsum, N);
    k_scan_mid<<<1, 64, 0, stream>>>(bsum, nblk);
    k_scan_add<<<(N + 256) / 256, 256, 0, stream>>>(bsum, rowp, N);
    k_place<<<egrid, 256, 0, stream>>>(srcp, dstp, E, N, rowp, rank, col);

    // layer 1 (gemm + fused att scalars; bf16 h)
    k_gemm<<<ggrid, 256, 0, stream>>>(x, W1, hbuf, as1, ad1, asrc, adst, N);
    k_aggregate<<<N, 256, 0, stream>>>(hbuf, asrc, adst, rowp, col, b1,
                                       obuf, nullptr, nullptr, nullptr, N);

    // layer 2 (fc + sigmoid fused into epilogue)
    k_gemm<<<ggrid, 256, 0, stream>>>(obuf, W2, hbuf, as2, ad2, asrc, adst, N);
    k_aggregate<<<N, 256, 0, stream>>>(hbuf, asrc, adst, rowp, col, b2,
                                       nullptr, fcW, fcb, (float*)d_out, N);
}

// Round 6
// 314.755 us; speedup vs baseline: 2.4524x; 1.2582x over previous
//
#include <hip/hip_runtime.h>
#include <math.h>

#define FDIM 128
#define NEG_SLOPE 0.2f

__device__ __forceinline__ float lrelu(float x) {
    return x > 0.f ? x : NEG_SLOPE * x;
}

// bf16 helpers (RNE; inputs finite)
__device__ __forceinline__ unsigned short f2bf(float f) {
    unsigned u = __float_as_uint(f);
    return (unsigned short)((u + 0x7FFFu + ((u >> 16) & 1u)) >> 16);
}
__device__ __forceinline__ float bf2f(unsigned short h) {
    return __uint_as_float((unsigned)h << 16);
}

// ---------------- CSR build ----------------

__global__ __launch_bounds__(256) void k_rank(const int* __restrict__ dstp,
                                              int E, int N,
                                              int* __restrict__ cnt,
                                              unsigned short* __restrict__ rank) {
    int e = blockIdx.x * 256 + threadIdx.x;
    int total = E + N;
    if (e >= total) return;
    int d = (e < E) ? dstp[e] : (e - E);
    rank[e] = (unsigned short)atomicAdd(&cnt[d], 1);
}

__global__ __launch_bounds__(256) void k_scan_local(const int* __restrict__ deg,
                                                    int* __restrict__ rowp,
                                                    int* __restrict__ bsum, int n) {
    __shared__ int sh[256];
    int b = blockIdx.x, t = threadIdx.x;
    int base = b * 1024 + t * 4;
    int4 v = make_int4(0, 0, 0, 0);
    if (base + 3 < n) v = *(const int4*)(deg + base);
    else {
        if (base < n)     v.x = deg[base];
        if (base + 1 < n) v.y = deg[base + 1];
        if (base + 2 < n) v.z = deg[base + 2];
        if (base + 3 < n) v.w = deg[base + 3];
    }
    int s = v.x + v.y + v.z + v.w;
    sh[t] = s;
    __syncthreads();
    for (int off = 1; off < 256; off <<= 1) {
        int u = (t >= off) ? sh[t - off] : 0;
        __syncthreads();
        sh[t] += u;
        __syncthreads();
    }
    int excl = t ? sh[t - 1] : 0;
    int r0 = excl + v.x, r1 = r0 + v.y, r2 = r1 + v.z, r3 = r2 + v.w;
    if (base < n)     rowp[base + 1] = r0;
    if (base + 1 < n) rowp[base + 2] = r1;
    if (base + 2 < n) rowp[base + 3] = r2;
    if (base + 3 < n) rowp[base + 4] = r3;
    if (t == 255) bsum[b] = sh[255];
}

__global__ void k_scan_mid(int* __restrict__ bsum, int nb) {
    int lane = threadIdx.x;
    int own = (lane < nb) ? bsum[lane] : 0;
    int v = own;
    for (int off = 1; off < 64; off <<= 1) {
        int u = __shfl(v, lane - off);
        if (lane >= off) v += u;
    }
    if (lane < nb) bsum[lane] = v - own;  // exclusive
}

__global__ __launch_bounds__(256) void k_scan_add(const int* __restrict__ bsum,
                                                  int* __restrict__ rowp, int n) {
    int idx = blockIdx.x * 256 + threadIdx.x;
    if (idx > n) return;
    if (idx == 0) { rowp[0] = 0; return; }
    int blk = (idx - 1) >> 10;
    if (blk > 0) rowp[idx] += bsum[blk];
}

__global__ __launch_bounds__(256) void k_place(const int* __restrict__ srcp,
                                               const int* __restrict__ dstp,
                                               int E, int N,
                                               const int* __restrict__ rowp,
                                               const unsigned short* __restrict__ rank,
                                               int* __restrict__ col) {
    int e = blockIdx.x * 256 + threadIdx.x;
    int total = E + N;
    if (e >= total) return;
    int s, d;
    if (e < E) { s = srcp[e]; d = dstp[e]; }
    else       { s = d = e - E; }
    col[rowp[d] + rank[e]] = s;
}

// ---------------- GEMM (+ fused attention scalars): 64 rows/block ----------------

__global__ __launch_bounds__(256) void k_gemm(const float* __restrict__ A,
                                              const float* __restrict__ W,
                                              unsigned short* __restrict__ out,
                                              const float* __restrict__ att_s,
                                              const float* __restrict__ att_d,
                                              float* __restrict__ asrc,
                                              float* __restrict__ adst, int nrows) {
    __shared__ float Ws[FDIM * FDIM];
    __shared__ float sAs[FDIM], sAd[FDIM];
    int t = threadIdx.x;
    for (int f = t; f < FDIM * FDIM / 4; f += 256)
        ((float4*)Ws)[f] = ((const float4*)W)[f];
    if (t < FDIM) { sAs[t] = att_s[t]; sAd[t] = att_d[t]; }
    __syncthreads();

    int tx = t & 31;
    int ty = t >> 5;
    int row0 = blockIdx.x * 64 + ty * 8;

    float acc[8][4];
#pragma unroll
    for (int i = 0; i < 8; ++i)
#pragma unroll
        for (int j = 0; j < 4; ++j) acc[i][j] = 0.f;

    int rr[8];
#pragma unroll
    for (int i = 0; i < 8; ++i)
        rr[i] = (row0 + i < nrows) ? (row0 + i) : (nrows - 1);

#pragma unroll 2
    for (int k4 = 0; k4 < FDIM; k4 += 4) {
        float4 xv[8];
#pragma unroll
        for (int i = 0; i < 8; ++i)
            xv[i] = *(const float4*)(A + (size_t)rr[i] * FDIM + k4);
#pragma unroll
        for (int q = 0; q < 4; ++q) {
            float4 wv = *(float4*)&Ws[(k4 + q) * FDIM + tx * 4];
#pragma unroll
            for (int i = 0; i < 8; ++i) {
                float xs = (q == 0) ? xv[i].x : (q == 1) ? xv[i].y : (q == 2) ? xv[i].z : xv[i].w;
                acc[i][0] = fmaf(xs, wv.x, acc[i][0]);
                acc[i][1] = fmaf(xs, wv.y, acc[i][1]);
                acc[i][2] = fmaf(xs, wv.z, acc[i][2]);
                acc[i][3] = fmaf(xs, wv.w, acc[i][3]);
            }
        }
    }
#pragma unroll
    for (int i = 0; i < 8; ++i) {
        if (row0 + i < nrows) {
            ushort4 o;
            o.x = f2bf(acc[i][0]);
            o.y = f2bf(acc[i][1]);
            o.z = f2bf(acc[i][2]);
            o.w = f2bf(acc[i][3]);
            *(ushort4*)(out + (size_t)(row0 + i) * FDIM + tx * 4) = o;
        }
    }

    float ps[8], pd[8];
#pragma unroll
    for (int i = 0; i < 8; ++i) {
        float s = 0.f, d = 0.f;
#pragma unroll
        for (int j = 0; j < 4; ++j) {
            s = fmaf(acc[i][j], sAs[tx * 4 + j], s);
            d = fmaf(acc[i][j], sAd[tx * 4 + j], d);
        }
        ps[i] = s; pd[i] = d;
    }
#pragma unroll
    for (int off = 8; off; off >>= 1) {
#pragma unroll
        for (int i = 0; i < 8; ++i) {
            ps[i] += __shfl_xor(ps[i], off);
            pd[i] += __shfl_xor(pd[i], off);
        }
    }
    if ((tx & 15) == 0) {
        int head = tx >> 4;
#pragma unroll
        for (int i = 0; i < 8; ++i) {
            if (row0 + i < nrows) {
                asrc[2 * (row0 + i) + head] = ps[i];
                adst[2 * (row0 + i) + head] = pd[i];
            }
        }
    }
}

// ---------------- per-dst softmax + aggregation: ONE WAVE PER NODE ----------------
// 4 nodes per 256-thread block; no __syncthreads anywhere (same-wave LDS only).
// Key identity: out = (sum_i e_i * h_i) * inv  — unnormalized e_i in LDS, one
// final scale. Online per-64-edge-chunk rescale makes it deg-generic.
// Lane c owns channels 2c,2c+1; lanes<32 = head0, lanes>=32 = head1.

__global__ __launch_bounds__(256) void k_aggregate(const unsigned short* __restrict__ h,
                                                   const float* __restrict__ asrc,
                                                   const float* __restrict__ adst,
                                                   const int* __restrict__ rowp,
                                                   const int* __restrict__ col,
                                                   const float* __restrict__ bias,
                                                   float* __restrict__ outbuf,
                                                   const float* __restrict__ fcW,
                                                   const float* __restrict__ fcb,
                                                   float* __restrict__ outfin, int n) {
    __shared__ int   scol[4][64];
    __shared__ float sal0[4][64], sal1[4][64];

    int t = threadIdx.x;
    int w = t >> 6;
    int lane = t & 63;
    int node = blockIdx.x * 4 + w;
    if (node >= n) return;

    int start = rowp[node];
    int deg = rowp[node + 1] - start;
    float2 adv = *(const float2*)(adst + 2 * node);
    float ad0 = adv.x, ad1 = adv.y;
    const ushort2* __restrict__ hb = (const ushort2*)h;
    const float* __restrict__ amy = (lane < 32) ? sal0[w] : sal1[w];

    float m0 = -1e30f, m1 = -1e30f;   // running maxes
    float p0 = 0.f, p1 = 0.f;         // per-lane partial sums of e
    float accx = 0.f, accy = 0.f;     // per-lane weighted h accumulator

    for (int base = 0; base < deg; base += 64) {
        int cnt = min(64, deg - base);
        // ---- load + value ----
        float v0 = -1e30f, v1 = -1e30f;
        if (lane < cnt) {
            int s = col[start + base + lane];
            scol[w][lane] = s;
            float2 av = *(const float2*)(asrc + 2 * s);
            v0 = lrelu(av.x + ad0);
            v1 = lrelu(av.y + ad1);
        }
        // ---- chunk max (in-wave) ----
        float c0 = v0, c1 = v1;
#pragma unroll
        for (int off = 32; off; off >>= 1) {
            c0 = fmaxf(c0, __shfl_xor(c0, off));
            c1 = fmaxf(c1, __shfl_xor(c1, off));
        }
        float nm0 = fmaxf(m0, c0), nm1 = fmaxf(m1, c1);
        float r0 = __expf(m0 - nm0), r1 = __expf(m1 - nm1);
        m0 = nm0; m1 = nm1;
        p0 *= r0; p1 *= r1;
        float rmy = (lane < 32) ? r0 : r1;
        accx *= rmy; accy *= rmy;
        // ---- e (unnormalized), stored to LDS ----
        float e0 = (lane < cnt) ? __expf(v0 - m0) : 0.f;
        float e1 = (lane < cnt) ? __expf(v1 - m1) : 0.f;
        p0 += e0; p1 += e1;
        sal0[w][lane] = e0;
        sal1[w][lane] = e1;
        // ---- gather: 4 independent chains over this chunk ----
        float2 g0 = make_float2(0.f, 0.f), g1 = make_float2(0.f, 0.f);
        float2 g2 = make_float2(0.f, 0.f), g3 = make_float2(0.f, 0.f);
        int i = 0;
        for (; i + 3 < cnt; i += 4) {
            unsigned sa = (unsigned)scol[w][i];
            unsigned sb = (unsigned)scol[w][i + 1];
            unsigned sc = (unsigned)scol[w][i + 2];
            unsigned sd = (unsigned)scol[w][i + 3];
            float wa = amy[i], wb = amy[i + 1], wc = amy[i + 2], wd = amy[i + 3];
            ushort2 ha = hb[sa * 64u + lane];
            ushort2 hv = hb[sb * 64u + lane];
            ushort2 hc = hb[sc * 64u + lane];
            ushort2 hd = hb[sd * 64u + lane];
            g0.x = fmaf(bf2f(ha.x), wa, g0.x); g0.y = fmaf(bf2f(ha.y), wa, g0.y);
            g1.x = fmaf(bf2f(hv.x), wb, g1.x); g1.y = fmaf(bf2f(hv.y), wb, g1.y);
            g2.x = fmaf(bf2f(hc.x), wc, g2.x); g2.y = fmaf(bf2f(hc.y), wc, g2.y);
            g3.x = fmaf(bf2f(hd.x), wd, g3.x); g3.y = fmaf(bf2f(hd.y), wd, g3.y);
        }
        for (; i < cnt; ++i) {
            unsigned s = (unsigned)scol[w][i];
            float a = amy[i];
            ushort2 hv = hb[s * 64u + lane];
            g0.x = fmaf(bf2f(hv.x), a, g0.x);
            g0.y = fmaf(bf2f(hv.y), a, g0.y);
        }
        accx += g0.x + g1.x + g2.x + g3.x;
        accy += g0.y + g1.y + g2.y + g3.y;
    }

    // ---- final: reduce partial sums across lanes, scale once ----
#pragma unroll
    for (int off = 32; off; off >>= 1) {
        p0 += __shfl_xor(p0, off);
        p1 += __shfl_xor(p1, off);
    }
    float invmy = (lane < 32) ? 1.f / (p0 + 1e-16f) : 1.f / (p1 + 1e-16f);
    accx *= invmy;
    accy *= invmy;

    int c0i = 2 * lane, c1i = 2 * lane + 1;
    float2 bv = *(const float2*)(bias + c0i);
    float o0 = fmaxf(accx + bv.x, 0.f);
    float o1 = fmaxf(accy + bv.y, 0.f);
    if (outbuf)
        *(float2*)(outbuf + (size_t)node * FDIM + c0i) = make_float2(o0, o1);
    if (outfin) {
        float2 fv = *(const float2*)(fcW + c0i);
        float p = fmaf(o0, fv.x, o1 * fv.y);
#pragma unroll
        for (int off = 32; off; off >>= 1) p += __shfl_xor(p, off);
        if (lane == 0) outfin[node] = 1.f / (1.f + __expf(-(p + fcb[0])));
    }
}

// ---------------- host ----------------

static inline size_t rnd256(size_t x) { return (x + 255) & ~(size_t)255; }

extern "C" void kernel_launch(void* const* d_in, const int* in_sizes, int n_in,
                              void* d_out, int out_size, void* d_ws, size_t ws_size,
                              hipStream_t stream) {
    const float* x    = (const float*)d_in[0];
    const int*   ei   = (const int*)d_in[1];
    const float* W1   = (const float*)d_in[3];
    const float* as1  = (const float*)d_in[4];
    const float* ad1  = (const float*)d_in[5];
    const float* b1   = (const float*)d_in[6];
    const float* W2   = (const float*)d_in[7];
    const float* as2  = (const float*)d_in[8];
    const float* ad2  = (const float*)d_in[9];
    const float* b2   = (const float*)d_in[10];
    const float* fcW  = (const float*)d_in[11];
    const float* fcb  = (const float*)d_in[12];

    int N = in_sizes[0] / FDIM;
    int E = in_sizes[2];
    int E2 = E + N;
    const int* srcp = ei;
    const int* dstp = ei + E;

    char* w = (char*)d_ws;
    unsigned short* hbuf = (unsigned short*)w; w += rnd256((size_t)N * FDIM * sizeof(unsigned short));
    float* obuf = (float*)w;  w += rnd256((size_t)N * FDIM * sizeof(float));
    float* asrc = (float*)w;  w += rnd256((size_t)N * 2 * sizeof(float));
    float* adst = (float*)w;  w += rnd256((size_t)N * 2 * sizeof(float));
    int* rowp = (int*)w;      w += rnd256((size_t)(N + 1) * sizeof(int));
    int* cnt  = (int*)w;      w += rnd256((size_t)N * sizeof(int));
    int* bsum = (int*)w;      w += rnd256((size_t)256 * sizeof(int));
    unsigned short* rank = (unsigned short*)w; w += rnd256((size_t)E2 * sizeof(unsigned short));
    int* col  = (int*)w;      w += rnd256((size_t)E2 * sizeof(int));

    int egrid = (E2 + 255) / 256;
    int ggrid = (N + 63) / 64;
    int nblk = (N + 1023) / 1024;
    int agrid = (N + 3) / 4;

    // CSR build (shared by both layers)
    hipMemsetAsync(cnt, 0, (size_t)N * sizeof(int), stream);
    k_rank<<<egrid, 256, 0, stream>>>(dstp, E, N, cnt, rank);
    k_scan_local<<<nblk, 256, 0, stream>>>(cnt, rowp, bsum, N);
    k_scan_mid<<<1, 64, 0, stream>>>(bsum, nblk);
    k_scan_add<<<(N + 256) / 256, 256, 0, stream>>>(bsum, rowp, N);
    k_place<<<egrid, 256, 0, stream>>>(srcp, dstp, E, N, rowp, rank, col);

    // layer 1 (gemm + fused att scalars; bf16 h)
    k_gemm<<<ggrid, 256, 0, stream>>>(x, W1, hbuf, as1, ad1, asrc, adst, N);
    k_aggregate<<<agrid, 256, 0, stream>>>(hbuf, asrc, adst, rowp, col, b1,
                                           obuf, nullptr, nullptr, nullptr, N);

    // layer 2 (fc + sigmoid fused into epilogue)
    k_gemm<<<ggrid, 256, 0, stream>>>(obuf, W2, hbuf, as2, ad2, asrc, adst, N);
    k_aggregate<<<agrid, 256, 0, stream>>>(hbuf, asrc, adst, rowp, col, b2,
                                           nullptr, fcW, fcb, (float*)d_out, N);
}

// Round 7
// 308.690 us; speedup vs baseline: 2.5006x; 1.0196x over previous
//
#include <hip/hip_runtime.h>
#include <math.h>

#define FDIM 128
#define NEG_SLOPE 0.2f

__device__ __forceinline__ float lrelu(float x) {
    return x > 0.f ? x : NEG_SLOPE * x;
}

// bf16 helpers (RNE; inputs finite)
__device__ __forceinline__ unsigned short f2bf(float f) {
    unsigned u = __float_as_uint(f);
    return (unsigned short)((u + 0x7FFFu + ((u >> 16) & 1u)) >> 16);
}
__device__ __forceinline__ float bf2f(unsigned short h) {
    return __uint_as_float((unsigned)h << 16);
}

// ---------------- fused GEMM-1 + rank ----------------
// Blocks [0, rgrid): rank pass — rank[e] = atomicAdd(&cnt[dst*stride], 1),
//   4 edges/thread (independent atomics), counters line-padded to kill
//   cache-line convoying. Scheduled first (long pole, atomic-bound).
// Blocks [rgrid, rgrid+ggrid): GEMM h = A@W (+ fused attention scalars),
//   VALU-bound — overlaps the atomic-bound rank blocks.

__global__ __launch_bounds__(256) void k_gemm_rank(
    // rank args
    const int* __restrict__ dstp, int E, int N,
    int* __restrict__ cnt, int stride, unsigned short* __restrict__ rank,
    int rgrid,
    // gemm args
    const float* __restrict__ A, const float* __restrict__ W,
    unsigned short* __restrict__ out,
    const float* __restrict__ att_s, const float* __restrict__ att_d,
    float* __restrict__ asrc, float* __restrict__ adst, int nrows) {
    __shared__ float Ws[FDIM * FDIM];
    __shared__ float sAs[FDIM], sAd[FDIM];

    int t = threadIdx.x;
    if ((int)blockIdx.x < rgrid) {
        // ---------------- rank path ----------------
        int total = E + N;
        int e0 = (blockIdx.x * 256 + t) * 4;
        if (e0 >= total) return;
        if (e0 + 3 < E) {
            int4 d4 = *(const int4*)(dstp + e0);
            ushort4 r;
            r.x = (unsigned short)atomicAdd(&cnt[d4.x * stride], 1);
            r.y = (unsigned short)atomicAdd(&cnt[d4.y * stride], 1);
            r.z = (unsigned short)atomicAdd(&cnt[d4.z * stride], 1);
            r.w = (unsigned short)atomicAdd(&cnt[d4.w * stride], 1);
            *(ushort4*)(rank + e0) = r;
        } else {
#pragma unroll
            for (int q = 0; q < 4; ++q) {
                int e = e0 + q;
                if (e < total) {
                    int d = (e < E) ? dstp[e] : (e - E);
                    rank[e] = (unsigned short)atomicAdd(&cnt[d * stride], 1);
                }
            }
        }
        return;
    }

    // ---------------- GEMM path ----------------
    for (int f = t; f < FDIM * FDIM / 4; f += 256)
        ((float4*)Ws)[f] = ((const float4*)W)[f];
    if (t < FDIM) { sAs[t] = att_s[t]; sAd[t] = att_d[t]; }
    __syncthreads();

    int tx = t & 31;
    int ty = t >> 5;
    int row0 = ((int)blockIdx.x - rgrid) * 64 + ty * 8;

    float acc[8][4];
#pragma unroll
    for (int i = 0; i < 8; ++i)
#pragma unroll
        for (int j = 0; j < 4; ++j) acc[i][j] = 0.f;

    int rr[8];
#pragma unroll
    for (int i = 0; i < 8; ++i)
        rr[i] = (row0 + i < nrows) ? (row0 + i) : (nrows - 1);

#pragma unroll 2
    for (int k4 = 0; k4 < FDIM; k4 += 4) {
        float4 xv[8];
#pragma unroll
        for (int i = 0; i < 8; ++i)
            xv[i] = *(const float4*)(A + (size_t)rr[i] * FDIM + k4);
#pragma unroll
        for (int q = 0; q < 4; ++q) {
            float4 wv = *(float4*)&Ws[(k4 + q) * FDIM + tx * 4];
#pragma unroll
            for (int i = 0; i < 8; ++i) {
                float xs = (q == 0) ? xv[i].x : (q == 1) ? xv[i].y : (q == 2) ? xv[i].z : xv[i].w;
                acc[i][0] = fmaf(xs, wv.x, acc[i][0]);
                acc[i][1] = fmaf(xs, wv.y, acc[i][1]);
                acc[i][2] = fmaf(xs, wv.z, acc[i][2]);
                acc[i][3] = fmaf(xs, wv.w, acc[i][3]);
            }
        }
    }
#pragma unroll
    for (int i = 0; i < 8; ++i) {
        if (row0 + i < nrows) {
            ushort4 o;
            o.x = f2bf(acc[i][0]);
            o.y = f2bf(acc[i][1]);
            o.z = f2bf(acc[i][2]);
            o.w = f2bf(acc[i][3]);
            *(ushort4*)(out + (size_t)(row0 + i) * FDIM + tx * 4) = o;
        }
    }

    float ps[8], pd[8];
#pragma unroll
    for (int i = 0; i < 8; ++i) {
        float s = 0.f, d = 0.f;
#pragma unroll
        for (int j = 0; j < 4; ++j) {
            s = fmaf(acc[i][j], sAs[tx * 4 + j], s);
            d = fmaf(acc[i][j], sAd[tx * 4 + j], d);
        }
        ps[i] = s; pd[i] = d;
    }
#pragma unroll
    for (int off = 8; off; off >>= 1) {
#pragma unroll
        for (int i = 0; i < 8; ++i) {
            ps[i] += __shfl_xor(ps[i], off);
            pd[i] += __shfl_xor(pd[i], off);
        }
    }
    if ((tx & 15) == 0) {
        int head = tx >> 4;
#pragma unroll
        for (int i = 0; i < 8; ++i) {
            if (row0 + i < nrows) {
                asrc[2 * (row0 + i) + head] = ps[i];
                adst[2 * (row0 + i) + head] = pd[i];
            }
        }
    }
}

// ---------------- standalone GEMM (layer 2) ----------------

__global__ __launch_bounds__(256) void k_gemm(const float* __restrict__ A,
                                              const float* __restrict__ W,
                                              unsigned short* __restrict__ out,
                                              const float* __restrict__ att_s,
                                              const float* __restrict__ att_d,
                                              float* __restrict__ asrc,
                                              float* __restrict__ adst, int nrows) {
    __shared__ float Ws[FDIM * FDIM];
    __shared__ float sAs[FDIM], sAd[FDIM];
    int t = threadIdx.x;
    for (int f = t; f < FDIM * FDIM / 4; f += 256)
        ((float4*)Ws)[f] = ((const float4*)W)[f];
    if (t < FDIM) { sAs[t] = att_s[t]; sAd[t] = att_d[t]; }
    __syncthreads();

    int tx = t & 31;
    int ty = t >> 5;
    int row0 = blockIdx.x * 64 + ty * 8;

    float acc[8][4];
#pragma unroll
    for (int i = 0; i < 8; ++i)
#pragma unroll
        for (int j = 0; j < 4; ++j) acc[i][j] = 0.f;

    int rr[8];
#pragma unroll
    for (int i = 0; i < 8; ++i)
        rr[i] = (row0 + i < nrows) ? (row0 + i) : (nrows - 1);

#pragma unroll 2
    for (int k4 = 0; k4 < FDIM; k4 += 4) {
        float4 xv[8];
#pragma unroll
        for (int i = 0; i < 8; ++i)
            xv[i] = *(const float4*)(A + (size_t)rr[i] * FDIM + k4);
#pragma unroll
        for (int q = 0; q < 4; ++q) {
            float4 wv = *(float4*)&Ws[(k4 + q) * FDIM + tx * 4];
#pragma unroll
            for (int i = 0; i < 8; ++i) {
                float xs = (q == 0) ? xv[i].x : (q == 1) ? xv[i].y : (q == 2) ? xv[i].z : xv[i].w;
                acc[i][0] = fmaf(xs, wv.x, acc[i][0]);
                acc[i][1] = fmaf(xs, wv.y, acc[i][1]);
                acc[i][2] = fmaf(xs, wv.z, acc[i][2]);
                acc[i][3] = fmaf(xs, wv.w, acc[i][3]);
            }
        }
    }
#pragma unroll
    for (int i = 0; i < 8; ++i) {
        if (row0 + i < nrows) {
            ushort4 o;
            o.x = f2bf(acc[i][0]);
            o.y = f2bf(acc[i][1]);
            o.z = f2bf(acc[i][2]);
            o.w = f2bf(acc[i][3]);
            *(ushort4*)(out + (size_t)(row0 + i) * FDIM + tx * 4) = o;
        }
    }

    float ps[8], pd[8];
#pragma unroll
    for (int i = 0; i < 8; ++i) {
        float s = 0.f, d = 0.f;
#pragma unroll
        for (int j = 0; j < 4; ++j) {
            s = fmaf(acc[i][j], sAs[tx * 4 + j], s);
            d = fmaf(acc[i][j], sAd[tx * 4 + j], d);
        }
        ps[i] = s; pd[i] = d;
    }
#pragma unroll
    for (int off = 8; off; off >>= 1) {
#pragma unroll
        for (int i = 0; i < 8; ++i) {
            ps[i] += __shfl_xor(ps[i], off);
            pd[i] += __shfl_xor(pd[i], off);
        }
    }
    if ((tx & 15) == 0) {
        int head = tx >> 4;
#pragma unroll
        for (int i = 0; i < 8; ++i) {
            if (row0 + i < nrows) {
                asrc[2 * (row0 + i) + head] = ps[i];
                adst[2 * (row0 + i) + head] = pd[i];
            }
        }
    }
}

// ---------------- scan over padded counters ----------------

__global__ __launch_bounds__(256) void k_scan_local(const int* __restrict__ deg,
                                                    int stride,
                                                    int* __restrict__ rowp,
                                                    int* __restrict__ bsum, int n) {
    __shared__ int sh[256];
    int b = blockIdx.x, t = threadIdx.x;
    int base = b * 1024 + t * 4;
    int4 v = make_int4(0, 0, 0, 0);
    if (base < n)     v.x = deg[(size_t)base * stride];
    if (base + 1 < n) v.y = deg[(size_t)(base + 1) * stride];
    if (base + 2 < n) v.z = deg[(size_t)(base + 2) * stride];
    if (base + 3 < n) v.w = deg[(size_t)(base + 3) * stride];
    int s = v.x + v.y + v.z + v.w;
    sh[t] = s;
    __syncthreads();
    for (int off = 1; off < 256; off <<= 1) {
        int u = (t >= off) ? sh[t - off] : 0;
        __syncthreads();
        sh[t] += u;
        __syncthreads();
    }
    int excl = t ? sh[t - 1] : 0;
    int r0 = excl + v.x, r1 = r0 + v.y, r2 = r1 + v.z, r3 = r2 + v.w;
    if (base < n)     rowp[base + 1] = r0;
    if (base + 1 < n) rowp[base + 2] = r1;
    if (base + 2 < n) rowp[base + 3] = r2;
    if (base + 3 < n) rowp[base + 4] = r3;
    if (t == 255) bsum[b] = sh[255];
}

__global__ void k_scan_mid(int* __restrict__ bsum, int nb) {
    int lane = threadIdx.x;
    int own = (lane < nb) ? bsum[lane] : 0;
    int v = own;
    for (int off = 1; off < 64; off <<= 1) {
        int u = __shfl(v, lane - off);
        if (lane >= off) v += u;
    }
    if (lane < nb) bsum[lane] = v - own;  // exclusive
}

__global__ __launch_bounds__(256) void k_scan_add(const int* __restrict__ bsum,
                                                  int* __restrict__ rowp, int n) {
    int idx = blockIdx.x * 256 + threadIdx.x;
    if (idx > n) return;
    if (idx == 0) { rowp[0] = 0; return; }
    int blk = (idx - 1) >> 10;
    if (blk > 0) rowp[idx] += bsum[blk];
}

// ---------------- place (4 edges/thread) ----------------

__global__ __launch_bounds__(256) void k_place(const int* __restrict__ srcp,
                                               const int* __restrict__ dstp,
                                               int E, int N,
                                               const int* __restrict__ rowp,
                                               const unsigned short* __restrict__ rank,
                                               int* __restrict__ col) {
    int total = E + N;
    int e0 = (blockIdx.x * 256 + threadIdx.x) * 4;
    if (e0 >= total) return;
    if (e0 + 3 < E) {
        int4 s4 = *(const int4*)(srcp + e0);
        int4 d4 = *(const int4*)(dstp + e0);
        ushort4 r4 = *(const ushort4*)(rank + e0);
        col[rowp[d4.x] + r4.x] = s4.x;
        col[rowp[d4.y] + r4.y] = s4.y;
        col[rowp[d4.z] + r4.z] = s4.z;
        col[rowp[d4.w] + r4.w] = s4.w;
    } else {
#pragma unroll
        for (int q = 0; q < 4; ++q) {
            int e = e0 + q;
            if (e < total) {
                int s, d;
                if (e < E) { s = srcp[e]; d = dstp[e]; }
                else       { s = d = e - E; }
                col[rowp[d] + rank[e]] = s;
            }
        }
    }
}

// ---------------- per-dst softmax + aggregation: ONE WAVE PER NODE ----------------

__global__ __launch_bounds__(256) void k_aggregate(const unsigned short* __restrict__ h,
                                                   const float* __restrict__ asrc,
                                                   const float* __restrict__ adst,
                                                   const int* __restrict__ rowp,
                                                   const int* __restrict__ col,
                                                   const float* __restrict__ bias,
                                                   float* __restrict__ outbuf,
                                                   const float* __restrict__ fcW,
                                                   const float* __restrict__ fcb,
                                                   float* __restrict__ outfin, int n) {
    __shared__ int   scol[4][64];
    __shared__ float sal0[4][64], sal1[4][64];

    int t = threadIdx.x;
    int w = t >> 6;
    int lane = t & 63;
    int node = blockIdx.x * 4 + w;
    if (node >= n) return;

    int start = rowp[node];
    int deg = rowp[node + 1] - start;
    float2 adv = *(const float2*)(adst + 2 * node);
    float ad0 = adv.x, ad1 = adv.y;
    const ushort2* __restrict__ hb = (const ushort2*)h;
    const float* __restrict__ amy = (lane < 32) ? sal0[w] : sal1[w];

    float m0 = -1e30f, m1 = -1e30f;
    float p0 = 0.f, p1 = 0.f;
    float accx = 0.f, accy = 0.f;

    for (int base = 0; base < deg; base += 64) {
        int cnt = min(64, deg - base);
        float v0 = -1e30f, v1 = -1e30f;
        if (lane < cnt) {
            int s = col[start + base + lane];
            scol[w][lane] = s;
            float2 av = *(const float2*)(asrc + 2 * s);
            v0 = lrelu(av.x + ad0);
            v1 = lrelu(av.y + ad1);
        }
        float c0 = v0, c1 = v1;
#pragma unroll
        for (int off = 32; off; off >>= 1) {
            c0 = fmaxf(c0, __shfl_xor(c0, off));
            c1 = fmaxf(c1, __shfl_xor(c1, off));
        }
        float nm0 = fmaxf(m0, c0), nm1 = fmaxf(m1, c1);
        float r0 = __expf(m0 - nm0), r1 = __expf(m1 - nm1);
        m0 = nm0; m1 = nm1;
        p0 *= r0; p1 *= r1;
        float rmy = (lane < 32) ? r0 : r1;
        accx *= rmy; accy *= rmy;
        float e0 = (lane < cnt) ? __expf(v0 - m0) : 0.f;
        float e1 = (lane < cnt) ? __expf(v1 - m1) : 0.f;
        p0 += e0; p1 += e1;
        sal0[w][lane] = e0;
        sal1[w][lane] = e1;
        float2 g0 = make_float2(0.f, 0.f), g1 = make_float2(0.f, 0.f);
        float2 g2 = make_float2(0.f, 0.f), g3 = make_float2(0.f, 0.f);
        int i = 0;
        for (; i + 3 < cnt; i += 4) {
            unsigned sa = (unsigned)scol[w][i];
            unsigned sb = (unsigned)scol[w][i + 1];
            unsigned sc = (unsigned)scol[w][i + 2];
            unsigned sd = (unsigned)scol[w][i + 3];
            float wa = amy[i], wb = amy[i + 1], wc = amy[i + 2], wd = amy[i + 3];
            ushort2 ha = hb[sa * 64u + lane];
            ushort2 hv = hb[sb * 64u + lane];
            ushort2 hc = hb[sc * 64u + lane];
            ushort2 hd = hb[sd * 64u + lane];
            g0.x = fmaf(bf2f(ha.x), wa, g0.x); g0.y = fmaf(bf2f(ha.y), wa, g0.y);
            g1.x = fmaf(bf2f(hv.x), wb, g1.x); g1.y = fmaf(bf2f(hv.y), wb, g1.y);
            g2.x = fmaf(bf2f(hc.x), wc, g2.x); g2.y = fmaf(bf2f(hc.y), wc, g2.y);
            g3.x = fmaf(bf2f(hd.x), wd, g3.x); g3.y = fmaf(bf2f(hd.y), wd, g3.y);
        }
        for (; i < cnt; ++i) {
            unsigned s = (unsigned)scol[w][i];
            float a = amy[i];
            ushort2 hv = hb[s * 64u + lane];
            g0.x = fmaf(bf2f(hv.x), a, g0.x);
            g0.y = fmaf(bf2f(hv.y), a, g0.y);
        }
        accx += g0.x + g1.x + g2.x + g3.x;
        accy += g0.y + g1.y + g2.y + g3.y;
    }

#pragma unroll
    for (int off = 32; off; off >>= 1) {
        p0 += __shfl_xor(p0, off);
        p1 += __shfl_xor(p1, off);
    }
    float invmy = (lane < 32) ? 1.f / (p0 + 1e-16f) : 1.f / (p1 + 1e-16f);
    accx *= invmy;
    accy *= invmy;

    int c0i = 2 * lane, c1i = 2 * lane + 1;
    float2 bv = *(const float2*)(bias + c0i);
    float o0 = fmaxf(accx + bv.x, 0.f);
    float o1 = fmaxf(accy + bv.y, 0.f);
    if (outbuf)
        *(float2*)(outbuf + (size_t)node * FDIM + c0i) = make_float2(o0, o1);
    if (outfin) {
        float2 fv = *(const float2*)(fcW + c0i);
        float p = fmaf(o0, fv.x, o1 * fv.y);
#pragma unroll
        for (int off = 32; off; off >>= 1) p += __shfl_xor(p, off);
        if (lane == 0) outfin[node] = 1.f / (1.f + __expf(-(p + fcb[0])));
    }
}

// ---------------- host ----------------

static inline size_t rnd256(size_t x) { return (x + 255) & ~(size_t)255; }

extern "C" void kernel_launch(void* const* d_in, const int* in_sizes, int n_in,
                              void* d_out, int out_size, void* d_ws, size_t ws_size,
                              hipStream_t stream) {
    const float* x    = (const float*)d_in[0];
    const int*   ei   = (const int*)d_in[1];
    const float* W1   = (const float*)d_in[3];
    const float* as1  = (const float*)d_in[4];
    const float* ad1  = (const float*)d_in[5];
    const float* b1   = (const float*)d_in[6];
    const float* W2   = (const float*)d_in[7];
    const float* as2  = (const float*)d_in[8];
    const float* ad2  = (const float*)d_in[9];
    const float* b2   = (const float*)d_in[10];
    const float* fcW  = (const float*)d_in[11];
    const float* fcb  = (const float*)d_in[12];

    int N = in_sizes[0] / FDIM;
    int E = in_sizes[2];
    int E2 = E + N;
    const int* srcp = ei;
    const int* dstp = ei + E;

    char* w = (char*)d_ws;
    unsigned short* hbuf = (unsigned short*)w; w += rnd256((size_t)N * FDIM * sizeof(unsigned short));
    float* obuf = (float*)w;  w += rnd256((size_t)N * FDIM * sizeof(float));
    float* asrc = (float*)w;  w += rnd256((size_t)N * 2 * sizeof(float));
    float* adst = (float*)w;  w += rnd256((size_t)N * 2 * sizeof(float));
    int* rowp = (int*)w;      w += rnd256((size_t)(N + 1) * sizeof(int));
    int* bsum = (int*)w;      w += rnd256((size_t)256 * sizeof(int));
    unsigned short* rank = (unsigned short*)w; w += rnd256((size_t)E2 * sizeof(unsigned short));
    int* col  = (int*)w;      w += rnd256((size_t)E2 * sizeof(int));
    // counters last: line-pad as far as the workspace allows (32 ints = 128B line)
    size_t used = (size_t)(w - (char*)d_ws);
    int stride = 32;
    while (stride > 1 && used + (size_t)N * stride * sizeof(int) > ws_size) stride >>= 1;
    int* cnt = (int*)w;

    int ggrid = (N + 63) / 64;
    int rgrid = (E2 + 1023) / 1024;
    int nblk = (N + 1023) / 1024;
    int agrid = (N + 3) / 4;

    hipMemsetAsync(cnt, 0, (size_t)N * stride * sizeof(int), stream);

    // fused: rank (atomic-bound, blocks first) + layer-1 GEMM (VALU-bound)
    k_gemm_rank<<<rgrid + ggrid, 256, 0, stream>>>(
        dstp, E, N, cnt, stride, rank, rgrid,
        x, W1, hbuf, as1, ad1, asrc, adst, N);

    // scan + place
    k_scan_local<<<nblk, 256, 0, stream>>>(cnt, stride, rowp, bsum, N);
    k_scan_mid<<<1, 64, 0, stream>>>(bsum, nblk);
    k_scan_add<<<(N + 256) / 256, 256, 0, stream>>>(bsum, rowp, N);
    k_place<<<(E2 + 1023) / 1024, 256, 0, stream>>>(srcp, dstp, E, N, rowp, rank, col);

    // layer 1 aggregate
    k_aggregate<<<agrid, 256, 0, stream>>>(hbuf, asrc, adst, rowp, col, b1,
                                           obuf, nullptr, nullptr, nullptr, N);

    // layer 2
    k_gemm<<<ggrid, 256, 0, stream>>>(obuf, W2, hbuf, as2, ad2, asrc, adst, N);
    k_aggregate<<<agrid, 256, 0, stream>>>(hbuf, asrc, adst, rowp, col, b2,
                                           nullptr, fcW, fcb, (float*)d_out, N);
}